// Round 2
// baseline (2752.979 us; speedup 1.0000x reference)
//
#include <hip/hip_runtime.h>

#define NG 100000
#define EG 400000
#define ELG 1200000
#define NT 50000
#define ET 100000
#define ELGT 300000

typedef unsigned short u16;
typedef unsigned int u32;

__device__ __forceinline__ float bflo(u32 p){ return __uint_as_float(p << 16); }
__device__ __forceinline__ float bfhi(u32 p){ return __uint_as_float(p & 0xffff0000u); }
__device__ __forceinline__ float bf2f(u16 h){ return __uint_as_float(((u32)h) << 16); }
__device__ __forceinline__ u16 f2bf(float f){
  u32 u = __float_as_uint(f);
  u32 r = u + 0x7fffu + ((u >> 16) & 1u);
  return (u16)(r >> 16);
}
__device__ __forceinline__ float sigm(float x){ return 1.0f / (1.0f + __expf(-x)); }
__device__ __forceinline__ float tanh_(float x){ return 2.0f / (1.0f + __expf(-2.0f * x)) - 1.0f; }
__device__ __forceinline__ float relu_(float x){ return x > 0.0f ? x : 0.0f; }

// ---------------- dtype sniffer ----------------
// Decide whether float-family inputs are bf16 (flag=1) or f32 (flag=0) by
// inspecting the low 16 bits of 4096 words of G_ef (~N(0,1) data):
//   bf16 pairs  -> low half is a bf16 value: exponent byte in [96,144] ~always
//   raw f32     -> low half = random mantissa bits: ~19% land in that range
//   bf16-rounded f32 -> low half == 0
__global__ void k_sniff(const u32* __restrict__ g, int* __restrict__ flag){
  __shared__ int sh[2];
  if (threadIdx.x < 2) sh[threadIdx.x] = 0;
  __syncthreads();
  int c0 = 0, c1 = 0;
  for (int i = 0; i < 16; i++){
    u32 w = g[threadIdx.x * 16 + i];
    u32 lo = w & 0xFFFFu;
    if (lo == 0u) c0++;
    else { u32 e = (lo >> 7) & 0xFFu; if (e >= 96u && e <= 144u) c1++; }
  }
  atomicAdd(&sh[0], c0); atomicAdd(&sh[1], c1);
  __syncthreads();
  if (threadIdx.x == 0) *flag = (sh[0] < 512 && sh[1] > 2048) ? 1 : 0;
}

// convert a weight matrix to an f32 mirror in ws (plain copy when already f32)
__global__ void k_cvtw(const void* __restrict__ src, float* __restrict__ dst, int n,
                       const int* __restrict__ flagp){
  int i = blockIdx.x * 256 + threadIdx.x;
  if (i >= n) return;
  if (*flagp) dst[i] = bf2f(((const u16*)src)[i]);
  else        dst[i] = ((const float*)src)[i];
}

// ---------------- dual-dtype row access ----------------
__device__ __forceinline__ const void* rowdt(const void* mat, size_t row, int W, int bf){
  return bf ? (const void*)((const u16*)mat + row * (size_t)W)
            : (const void*)((const float*)mat + row * (size_t)W);
}
// load 8 consecutive elements (chunk c8) of a row in either dtype
__device__ __forceinline__ void load8(const void* rowbase, int c8, int bf, float v[8]){
  if (bf){
    uint4 d = ((const uint4*)rowbase)[c8];
    v[0]=bflo(d.x); v[1]=bfhi(d.x); v[2]=bflo(d.y); v[3]=bfhi(d.y);
    v[4]=bflo(d.z); v[5]=bfhi(d.z); v[6]=bflo(d.w); v[7]=bfhi(d.w);
  } else {
    const float4* p = (const float4*)rowbase + (c8 << 1);
    float4 a = p[0], b = p[1];
    v[0]=a.x; v[1]=a.y; v[2]=a.z; v[3]=a.w; v[4]=b.x; v[5]=b.y; v[6]=b.z; v[7]=b.w;
  }
}
__device__ __forceinline__ void zero8(float v[8]){
  #pragma unroll
  for (int j = 0; j < 8; j++) v[j] = 0.f;
}
__device__ __forceinline__ void store8(float* p, const float v[8]){
  *(float4*)p     = make_float4(v[0], v[1], v[2], v[3]);
  *(float4*)(p+4) = make_float4(v[4], v[5], v[6], v[7]);
}

// ---------------- CSR build ----------------
__global__ void k_hist(const int* __restrict__ dst, int ne, int* __restrict__ cnt){
  int e = blockIdx.x * 256 + threadIdx.x;
  if (e < ne) atomicAdd(&cnt[dst[e]], 1);
}

__global__ void k_scan1(const int* __restrict__ cnt, int n, int* __restrict__ csum){
  int base = blockIdx.x * 4096, tid = threadIdx.x;
  int s = 0;
  for (int i = 0; i < 16; i++){ int idx = base + i * 256 + tid; if (idx < n) s += cnt[idx]; }
  __shared__ int red[4];
  for (int off = 32; off; off >>= 1) s += __shfl_down(s, off, 64);
  if ((tid & 63) == 0) red[tid >> 6] = s;
  __syncthreads();
  if (tid == 0) csum[blockIdx.x] = red[0] + red[1] + red[2] + red[3];
}

__global__ void k_scan2(int* csum, int nch, int* rowptr, int n){
  if (threadIdx.x == 0){
    int run = 0;
    for (int c = 0; c < nch; c++){ int t = csum[c]; csum[c] = run; run += t; }
    rowptr[n] = run;
  }
}

__global__ void k_scan3(const int* __restrict__ cnt, int n, const int* __restrict__ csum,
                        int* __restrict__ rowptr){
  __shared__ int buf[4096];
  __shared__ int tsum[256];
  int base = blockIdx.x * 4096, tid = threadIdx.x;
  for (int i = 0; i < 16; i++){ int idx = base + i * 256 + tid; buf[i * 256 + tid] = (idx < n) ? cnt[idx] : 0; }
  __syncthreads();
  int run = 0;
  for (int i = 0; i < 16; i++){ int v = buf[tid * 16 + i]; buf[tid * 16 + i] = run; run += v; }
  tsum[tid] = run;
  __syncthreads();
  for (int off = 1; off < 256; off <<= 1){
    int v = (tid >= off) ? tsum[tid - off] : 0;
    __syncthreads();
    tsum[tid] += v;
    __syncthreads();
  }
  int texcl = tsum[tid] - run;
  int cbase = csum[blockIdx.x];
  for (int i = 0; i < 16; i++){
    int idx = base + tid * 16 + i;
    if (idx < n) rowptr[idx] = cbase + texcl + buf[tid * 16 + i];
  }
}

__global__ void k_fill(const int* __restrict__ dst, const int* __restrict__ src, int ne,
                       const int* __restrict__ rowptr, int* __restrict__ fillcnt, int* __restrict__ col){
  int e = blockIdx.x * 256 + threadIdx.x;
  if (e >= ne) return;
  int d = dst[e];
  int pos = atomicAdd(&fillcnt[d], 1);
  col[rowptr[d] + pos] = src ? src[e] : e;
}

// ---------------- tile helpers (block = 256 threads, tile = 64 rows x 128 cols) ----------------

// gather-sum bf16 ws rows (via CSR) into f32 LDS tile [64][lda]
__device__ __forceinline__ void gather_sum(float* __restrict__ s_lds, int lda,
    const int* __restrict__ rowptr, const int* __restrict__ colidx,
    const u16* __restrict__ msg, int row0, int M)
{
  int tid = threadIdx.x;
  int rl = tid >> 2, q = tid & 3;
  int row = row0 + rl;
  float acc[4][8];
  #pragma unroll
  for (int v = 0; v < 4; v++)
    #pragma unroll
    for (int j = 0; j < 8; j++) acc[v][j] = 0.f;
  if (row < M){
    int p = rowptr[row], pe = rowptr[row + 1];
    for (; p < pe; ++p){
      int sr = colidx[p];
      const uint4* b = (const uint4*)(msg + (size_t)sr * 128);
      #pragma unroll
      for (int v = 0; v < 4; v++){
        uint4 d = b[v * 4 + q];
        acc[v][0] += bflo(d.x); acc[v][1] += bfhi(d.x);
        acc[v][2] += bflo(d.y); acc[v][3] += bfhi(d.y);
        acc[v][4] += bflo(d.z); acc[v][5] += bfhi(d.z);
        acc[v][6] += bflo(d.w); acc[v][7] += bfhi(d.w);
      }
    }
  }
  #pragma unroll
  for (int v = 0; v < 4; v++)
    store8(s_lds + rl * lda + (v * 4 + q) * 8, acc[v]);
}

// stage bf16 ws rows (optionally indexed) into f32 LDS tile [64][lda], 128 cols
__device__ __forceinline__ void stage_ws_bf16(float* __restrict__ a_lds, int lda,
    const u16* __restrict__ mat, const int* __restrict__ idx, int row0, int M)
{
  int tid = threadIdx.x;
  int rl = tid >> 2, q = tid & 3;
  int row = row0 + rl;
  float vals[4][8];
  #pragma unroll
  for (int v = 0; v < 4; v++) zero8(vals[v]);
  if (row < M){
    int sr = idx ? idx[row] : row;
    const uint4* b = (const uint4*)(mat + (size_t)sr * 128);
    #pragma unroll
    for (int v = 0; v < 4; v++){
      uint4 d = b[v * 4 + q];
      vals[v][0] = bflo(d.x); vals[v][1] = bfhi(d.x);
      vals[v][2] = bflo(d.y); vals[v][3] = bfhi(d.y);
      vals[v][4] = bflo(d.z); vals[v][5] = bfhi(d.z);
      vals[v][6] = bflo(d.w); vals[v][7] = bfhi(d.w);
    }
  }
  #pragma unroll
  for (int v = 0; v < 4; v++)
    store8(a_lds + rl * lda + (v * 4 + q) * 8, vals[v]);
}

// stage concat(Gf[Gsrc[row]], Gef[row]) (64+64, dual-dtype input) into LDS [64][lda]
__device__ __forceinline__ void stage_cat(float* __restrict__ lds, int lda,
    const void* __restrict__ Gf, const void* __restrict__ Gef, const int* __restrict__ Gsrc,
    int row0, int M, int bf)
{
  int tid = threadIdx.x, rl = tid >> 2, q = tid & 3;
  int row = row0 + rl;
  float A0[8], A1[8], B0[8], B1[8];
  if (row < M){
    int sr = Gsrc[row];
    const void* ra = rowdt(Gf, (size_t)sr, 64, bf);
    const void* rb = rowdt(Gef, (size_t)row, 64, bf);
    load8(ra, q, bf, A0); load8(ra, q + 4, bf, A1);
    load8(rb, q, bf, B0); load8(rb, q + 4, bf, B1);
  } else { zero8(A0); zero8(A1); zero8(B0); zero8(B1); }
  float* r = lds + rl * lda;
  store8(r + q * 8, A0);            store8(r + (q + 4) * 8, A1);
  store8(r + 64 + q * 8, B0);       store8(r + 64 + (q + 4) * 8, B1);
}

// stage a 64-wide dual-dtype matrix row block into LDS [64][lda]
__device__ __forceinline__ void stage_w64(float* __restrict__ lds, int lda,
    const void* __restrict__ mat, int row0, int M, int bf)
{
  int tid = threadIdx.x, rl = tid >> 2, q = tid & 3;
  int row = row0 + rl;
  float A0[8], A1[8];
  if (row < M){
    const void* ra = rowdt(mat, (size_t)row, 64, bf);
    load8(ra, q, bf, A0); load8(ra, q + 4, bf, A1);
  } else { zero8(A0); zero8(A1); }
  float* r = lds + rl * lda;
  store8(r + q * 8, A0); store8(r + (q + 4) * 8, A1);
}

// acc[4][8] += A_lds(64 x K, lda) @ W(K x 128); thread (rowg=tid>>4, colg=tid&15)
__device__ __forceinline__ void gemm_tile(const float* __restrict__ a_lds, int lda,
    const float* __restrict__ W, int K, float (&acc)[4][8])
{
  int tid = threadIdx.x;
  int colg = tid & 15, rowg = tid >> 4;
  const float* a0 = a_lds + rowg * 4 * lda;
  const float* wp = W + colg * 8;
  for (int k0 = 0; k0 < K; k0 += 4){
    float4 a[4];
    #pragma unroll
    for (int i = 0; i < 4; i++) a[i] = *(const float4*)(a0 + i * lda + k0);
    #pragma unroll
    for (int kk = 0; kk < 4; kk++){
      float4 w0 = *(const float4*)(wp + (k0 + kk) * 128);
      float4 w1 = *(const float4*)(wp + (k0 + kk) * 128 + 4);
      #pragma unroll
      for (int i = 0; i < 4; i++){
        float av = (kk == 0) ? a[i].x : (kk == 1) ? a[i].y : (kk == 2) ? a[i].z : a[i].w;
        acc[i][0] = fmaf(av, w0.x, acc[i][0]);
        acc[i][1] = fmaf(av, w0.y, acc[i][1]);
        acc[i][2] = fmaf(av, w0.z, acc[i][2]);
        acc[i][3] = fmaf(av, w0.w, acc[i][3]);
        acc[i][4] = fmaf(av, w1.x, acc[i][4]);
        acc[i][5] = fmaf(av, w1.y, acc[i][5]);
        acc[i][6] = fmaf(av, w1.z, acc[i][6]);
        acc[i][7] = fmaf(av, w1.w, acc[i][7]);
      }
    }
  }
}

// dual-weight variant: accA += A@Wa, accB += A@Wb (shares A reads)
__device__ __forceinline__ void gemm_tile2(const float* __restrict__ a_lds, int lda,
    const float* __restrict__ Wa, const float* __restrict__ Wb, int K,
    float (&accA)[4][8], float (&accB)[4][8])
{
  int tid = threadIdx.x;
  int colg = tid & 15, rowg = tid >> 4;
  const float* a0 = a_lds + rowg * 4 * lda;
  const float* wa = Wa + colg * 8;
  const float* wb = Wb + colg * 8;
  for (int k0 = 0; k0 < K; k0 += 4){
    float4 a[4];
    #pragma unroll
    for (int i = 0; i < 4; i++) a[i] = *(const float4*)(a0 + i * lda + k0);
    #pragma unroll
    for (int kk = 0; kk < 4; kk++){
      float4 wa0 = *(const float4*)(wa + (k0 + kk) * 128);
      float4 wa1 = *(const float4*)(wa + (k0 + kk) * 128 + 4);
      float4 wb0 = *(const float4*)(wb + (k0 + kk) * 128);
      float4 wb1 = *(const float4*)(wb + (k0 + kk) * 128 + 4);
      #pragma unroll
      for (int i = 0; i < 4; i++){
        float av = (kk == 0) ? a[i].x : (kk == 1) ? a[i].y : (kk == 2) ? a[i].z : a[i].w;
        accA[i][0] = fmaf(av, wa0.x, accA[i][0]);
        accA[i][1] = fmaf(av, wa0.y, accA[i][1]);
        accA[i][2] = fmaf(av, wa0.z, accA[i][2]);
        accA[i][3] = fmaf(av, wa0.w, accA[i][3]);
        accA[i][4] = fmaf(av, wa1.x, accA[i][4]);
        accA[i][5] = fmaf(av, wa1.y, accA[i][5]);
        accA[i][6] = fmaf(av, wa1.z, accA[i][6]);
        accA[i][7] = fmaf(av, wa1.w, accA[i][7]);
        accB[i][0] = fmaf(av, wb0.x, accB[i][0]);
        accB[i][1] = fmaf(av, wb0.y, accB[i][1]);
        accB[i][2] = fmaf(av, wb0.z, accB[i][2]);
        accB[i][3] = fmaf(av, wb0.w, accB[i][3]);
        accB[i][4] = fmaf(av, wb1.x, accB[i][4]);
        accB[i][5] = fmaf(av, wb1.y, accB[i][5]);
        accB[i][6] = fmaf(av, wb1.z, accB[i][6]);
        accB[i][7] = fmaf(av, wb1.w, accB[i][7]);
      }
    }
  }
}

#define ZERO48(A) { _Pragma("unroll") for (int i_=0;i_<4;i_++) _Pragma("unroll") for (int j_=0;j_<8;j_++) A[i_][j_]=0.f; }

// ---------------- pipeline kernels ----------------

// msg1 = relu(Gf[Gsrc]@W1 + Gef@W2)
__global__ __launch_bounds__(256) void k_baseG(const void* __restrict__ Gf, const void* __restrict__ Gef,
    const int* __restrict__ Gsrc, const float* __restrict__ W1, const float* __restrict__ W2,
    const int* __restrict__ flagp, u16* __restrict__ msg, int M)
{
  __shared__ alignas(16) float t_lds[64 * 132];
  int bf = *flagp;
  int row0 = blockIdx.x * 64;
  stage_cat(t_lds, 132, Gf, Gef, Gsrc, row0, M, bf);
  __syncthreads();
  float acc[4][8]; ZERO48(acc);
  gemm_tile(t_lds, 132, W1, 64, acc);
  gemm_tile(t_lds + 64, 132, W2, 64, acc);
  int colg = threadIdx.x & 15, rowg = threadIdx.x >> 4;
  #pragma unroll
  for (int i = 0; i < 4; i++){
    int grow = row0 + rowg * 4 + i;
    if (grow < M){
      union { uint4 v; u16 s[8]; } um;
      #pragma unroll
      for (int j = 0; j < 8; j++) um.s[j] = f2bf(relu_(acc[i][j]));
      *(uint4*)(msg + (size_t)grow * 128 + colg * 8) = um.v;
    }
  }
}

// msg_out = relu( (Gf[Gsrc]@W1 + Gef@W2) + segsum(msg_in)@W3 )   (base recomputed, f32 in regs)
__global__ __launch_bounds__(256) void k_iterG(const u16* __restrict__ msg_in, u16* __restrict__ msg_out,
    const void* __restrict__ Gf, const void* __restrict__ Gef, const int* __restrict__ Gsrc,
    const int* __restrict__ rowptr, const int* __restrict__ colidx,
    const float* __restrict__ W1, const float* __restrict__ W2, const float* __restrict__ W3,
    const int* __restrict__ flagp, int M)
{
  __shared__ alignas(16) float t_lds[64 * 132];
  int bf = *flagp;
  int row0 = blockIdx.x * 64;
  stage_cat(t_lds, 132, Gf, Gef, Gsrc, row0, M, bf);
  __syncthreads();
  float acc[4][8]; ZERO48(acc);
  gemm_tile(t_lds, 132, W1, 64, acc);
  gemm_tile(t_lds + 64, 132, W2, 64, acc);
  __syncthreads();                                    // done reading input tile
  gather_sum(t_lds, 132, rowptr, colidx, msg_in, row0, M);
  __syncthreads();
  gemm_tile(t_lds, 132, W3, 128, acc);
  int colg = threadIdx.x & 15, rowg = threadIdx.x >> 4;
  #pragma unroll
  for (int i = 0; i < 4; i++){
    int grow = row0 + rowg * 4 + i;
    if (grow < M){
      union { uint4 v; u16 s[8]; } um;
      #pragma unroll
      for (int j = 0; j < 8; j++) um.s[j] = f2bf(relu_(acc[i][j]));
      *(uint4*)(msg_out + (size_t)grow * 128 + colg * 8) = um.v;
    }
  }
}

// out = relu(Gf@U1 + segsum_dst(msg)@U2)
__global__ __launch_bounds__(256) void k_readoutG(const void* __restrict__ Gf,
    const u16* __restrict__ msg, const int* __restrict__ rowptr, const int* __restrict__ colidx,
    const float* __restrict__ U1, const float* __restrict__ U2, const int* __restrict__ flagp,
    float* __restrict__ out, int M)
{
  __shared__ alignas(16) float a1[64 * 68];
  __shared__ alignas(16) float s_lds[64 * 132];
  int bf = *flagp;
  int row0 = blockIdx.x * 64;
  stage_w64(a1, 68, Gf, row0, M, bf);
  gather_sum(s_lds, 132, rowptr, colidx, msg, row0, M);
  __syncthreads();
  float acc[4][8]; ZERO48(acc);
  gemm_tile(a1, 68, U1, 64, acc);
  gemm_tile(s_lds, 132, U2, 128, acc);
  int colg = threadIdx.x & 15, rowg = threadIdx.x >> 4;
  #pragma unroll
  for (int i = 0; i < 4; i++){
    int grow = row0 + rowg * 4 + i;
    if (grow < M){
      float* o = out + (size_t)grow * 128 + colg * 8;
      *(float4*)(o)     = make_float4(relu_(acc[i][0]), relu_(acc[i][1]), relu_(acc[i][2]), relu_(acc[i][3]));
      *(float4*)(o + 4) = make_float4(relu_(acc[i][4]), relu_(acc[i][5]), relu_(acc[i][6]), relu_(acc[i][7]));
    }
  }
}

// f_T = embeddings[T_id]  (bf16 ws, dual-dtype source)
__global__ void k_fT(const int* __restrict__ Tid, const void* __restrict__ emb,
                     const int* __restrict__ flagp, u16* __restrict__ fT){
  int g = blockIdx.x * 256 + threadIdx.x;
  if (g >= NT * 16) return;
  int bf = *flagp;
  int n = g >> 4, c8 = g & 15;
  const void* rb = rowdt(emb, (size_t)Tid[n], 128, bf);
  float t[8]; load8(rb, c8, bf, t);
  union { uint4 v; u16 h[8]; } u;
  #pragma unroll
  for (int j = 0; j < 8; j++) u.h[j] = f2bf(t[j]);
  *(uint4*)(fT + (size_t)n * 128 + c8 * 8) = u.v;
}

// xz/xr/xh = f_T[T_src]@{Wz,Wr,Wh}; msg1 = sigmoid(xz)*tanh(xh)
__global__ __launch_bounds__(256) void k_xzrh(const u16* __restrict__ fT, const int* __restrict__ Tsrc,
    const float* __restrict__ Wz, const float* __restrict__ Wr, const float* __restrict__ Wh,
    u16* __restrict__ xzrh, u16* __restrict__ msg, int M)
{
  __shared__ alignas(16) float a_lds[64 * 132];
  int row0 = blockIdx.x * 64;
  stage_ws_bf16(a_lds, 132, fT, Tsrc, row0, M);
  __syncthreads();
  int colg = threadIdx.x & 15, rowg = threadIdx.x >> 4;
  float accZ[4][8]; ZERO48(accZ);
  gemm_tile(a_lds, 132, Wz, 128, accZ);
  #pragma unroll
  for (int i = 0; i < 4; i++){
    int grow = row0 + rowg * 4 + i;
    if (grow < M){
      union { uint4 v; u16 s[8]; } u;
      #pragma unroll
      for (int j = 0; j < 8; j++) u.s[j] = f2bf(accZ[i][j]);
      *(uint4*)(xzrh + (size_t)grow * 384 + colg * 8) = u.v;
    }
  }
  float accT[4][8]; ZERO48(accT);
  gemm_tile(a_lds, 132, Wr, 128, accT);
  #pragma unroll
  for (int i = 0; i < 4; i++){
    int grow = row0 + rowg * 4 + i;
    if (grow < M){
      union { uint4 v; u16 s[8]; } u;
      #pragma unroll
      for (int j = 0; j < 8; j++) u.s[j] = f2bf(accT[i][j]);
      *(uint4*)(xzrh + (size_t)grow * 384 + 128 + colg * 8) = u.v;
    }
  }
  ZERO48(accT);
  gemm_tile(a_lds, 132, Wh, 128, accT);
  #pragma unroll
  for (int i = 0; i < 4; i++){
    int grow = row0 + rowg * 4 + i;
    if (grow < M){
      union { uint4 v; u16 s[8]; } uh, um;
      #pragma unroll
      for (int j = 0; j < 8; j++){
        uh.s[j] = f2bf(accT[i][j]);
        um.s[j] = f2bf(sigm(accZ[i][j]) * tanh_(accT[i][j]));
      }
      *(uint4*)(xzrh + (size_t)grow * 384 + 256 + colg * 8) = uh.v;
      *(uint4*)(msg  + (size_t)grow * 128 + colg * 8) = um.v;
    }
  }
}

// GRU step: s=segsum(msg); z=sig(xz+s@Uz); r=sig(xr+s@Ur); h=tanh(xh+(r*s)@Uh); msg=(1-z)s+zh
__global__ __launch_bounds__(256) void k_iterT(const u16* __restrict__ msg_in, const u16* __restrict__ xzrh,
    u16* __restrict__ msg_out, const int* __restrict__ rowptr, const int* __restrict__ colidx,
    const float* __restrict__ Uz, const float* __restrict__ Ur, const float* __restrict__ Uh, int M)
{
  __shared__ alignas(16) float s_lds[64 * 132];
  int row0 = blockIdx.x * 64;
  gather_sum(s_lds, 132, rowptr, colidx, msg_in, row0, M);
  __syncthreads();
  int colg = threadIdx.x & 15, rowg = threadIdx.x >> 4;
  float accZ[4][8], accR[4][8];
  ZERO48(accZ); ZERO48(accR);
  gemm_tile2(s_lds, 132, Uz, Ur, 128, accZ, accR);
  __syncthreads();  // all reads of s_lds done before we overwrite with r*s
  float z[4][8], sreg[4][8];
  #pragma unroll
  for (int i = 0; i < 4; i++){
    int row = rowg * 4 + i, grow = row0 + row;
    float* sp = s_lds + row * 132 + colg * 8;
    if (grow < M){
      union { uint4 v; u16 h[8]; } xz, xr;
      xz.v = *(const uint4*)(xzrh + (size_t)grow * 384 + colg * 8);
      xr.v = *(const uint4*)(xzrh + (size_t)grow * 384 + 128 + colg * 8);
      #pragma unroll
      for (int j = 0; j < 8; j++){
        float sv = sp[j];
        sreg[i][j] = sv;
        float zz = sigm(bf2f(xz.h[j]) + accZ[i][j]);
        float rr = sigm(bf2f(xr.h[j]) + accR[i][j]);
        z[i][j] = zz;
        sp[j] = rr * sv;   // tile becomes r*s
      }
    } else {
      #pragma unroll
      for (int j = 0; j < 8; j++){ z[i][j] = 0.f; sreg[i][j] = 0.f; sp[j] = 0.f; }
    }
  }
  __syncthreads();
  float accH[4][8]; ZERO48(accH);
  gemm_tile(s_lds, 132, Uh, 128, accH);
  #pragma unroll
  for (int i = 0; i < 4; i++){
    int grow = row0 + rowg * 4 + i;
    if (grow < M){
      union { uint4 v; u16 h[8]; } xh, om;
      xh.v = *(const uint4*)(xzrh + (size_t)grow * 384 + 256 + colg * 8);
      #pragma unroll
      for (int j = 0; j < 8; j++){
        float hh = tanh_(bf2f(xh.h[j]) + accH[i][j]);
        float m = (1.f - z[i][j]) * sreg[i][j] + z[i][j] * hh;
        om.h[j] = f2bf(m);
      }
      *(uint4*)(msg_out + (size_t)grow * 128 + colg * 8) = om.v;
    }
  }
}

// out = relu(f_T@U1 + segsum_dst(msg)@U2)   (single LDS tile, reused)
__global__ __launch_bounds__(256) void k_readoutT(const u16* __restrict__ fT,
    const u16* __restrict__ msg, const int* __restrict__ rowptr, const int* __restrict__ colidx,
    const float* __restrict__ U1, const float* __restrict__ U2, float* __restrict__ out, int M)
{
  __shared__ alignas(16) float t_lds[64 * 132];
  int row0 = blockIdx.x * 64;
  stage_ws_bf16(t_lds, 132, fT, nullptr, row0, M);
  __syncthreads();
  float acc[4][8]; ZERO48(acc);
  gemm_tile(t_lds, 132, U1, 128, acc);
  __syncthreads();  // done reading f_T tile
  gather_sum(t_lds, 132, rowptr, colidx, msg, row0, M);
  __syncthreads();
  gemm_tile(t_lds, 132, U2, 128, acc);
  int colg = threadIdx.x & 15, rowg = threadIdx.x >> 4;
  #pragma unroll
  for (int i = 0; i < 4; i++){
    int grow = row0 + rowg * 4 + i;
    if (grow < M){
      float* o = out + (size_t)grow * 128 + colg * 8;
      *(float4*)(o)     = make_float4(relu_(acc[i][0]), relu_(acc[i][1]), relu_(acc[i][2]), relu_(acc[i][3]));
      *(float4*)(o + 4) = make_float4(relu_(acc[i][4]), relu_(acc[i][5]), relu_(acc[i][6]), relu_(acc[i][7]));
    }
  }
}

// ---------------- host launcher ----------------
extern "C" void kernel_launch(void* const* d_in, const int* in_sizes, int n_in,
                              void* d_out, int out_size, void* d_ws, size_t ws_size,
                              hipStream_t stream)
{
  const void* G_f      = d_in[0];
  const void* G_ef     = d_in[1];
  const int*  G_src    = (const int*)d_in[2];
  const int*  G_dst    = (const int*)d_in[3];
  const int*  G_lg_src = (const int*)d_in[4];
  const int*  G_lg_dst = (const int*)d_in[5];
  const int*  T_id     = (const int*)d_in[6];
  const int*  T_src    = (const int*)d_in[7];
  const int*  T_dst    = (const int*)d_in[8];
  const int*  T_lg_src = (const int*)d_in[9];
  const int*  T_lg_dst = (const int*)d_in[10];
  const void* emb      = d_in[11];
  float* out = (float*)d_out;
  (void)in_sizes; (void)n_in; (void)out_size; (void)ws_size;

  size_t off = 0;
  auto alloc = [&](size_t bytes) -> char* {
    char* p = (char*)d_ws + off;
    off += (bytes + 255) & ~(size_t)255;
    return p;
  };

  int*   flag  = (int*)alloc(256);
  float* wm    = (float*)alloc(sizeof(float) * 188416);   // f32 weight mirrors
  float* wmW1  = wm;            // 8192
  float* wmW2  = wm + 8192;     // 8192
  float* wmW3  = wm + 16384;    // 16384
  float* wmU1G = wm + 32768;    // 8192
  float* wmU2G = wm + 40960;    // 16384
  float* wmWz  = wm + 57344;
  float* wmUz  = wm + 73728;
  float* wmWr  = wm + 90112;
  float* wmUr  = wm + 106496;
  float* wmWh  = wm + 122880;
  float* wmUh  = wm + 139264;
  float* wmU1T = wm + 155648;
  float* wmU2T = wm + 172032;

  int* rpG   = (int*)alloc(sizeof(int) * (EG + 1));
  int* colG  = (int*)alloc(sizeof(int) * ELG);
  int* rpGd  = (int*)alloc(sizeof(int) * (NG + 1));
  int* colGd = (int*)alloc(sizeof(int) * EG);
  int* rpT   = (int*)alloc(sizeof(int) * (ET + 1));
  int* colT  = (int*)alloc(sizeof(int) * ELGT);
  int* rpTd  = (int*)alloc(sizeof(int) * (NT + 1));
  int* colTd = (int*)alloc(sizeof(int) * ET);
  int* cnt   = (int*)alloc(sizeof(int) * 2 * EG);    // shared hist+fill scratch (max need)
  int* csum  = (int*)alloc(sizeof(int) * 128);
  u16* msgGA = (u16*)alloc((size_t)EG * 128 * 2);
  u16* msgGB = (u16*)alloc((size_t)EG * 128 * 2);
  u16* fT    = (u16*)alloc((size_t)NT * 128 * 2);
  u16* xzrh  = (u16*)alloc((size_t)ET * 384 * 2);
  u16* msgTA = (u16*)alloc((size_t)ET * 128 * 2);
  u16* msgTB = (u16*)alloc((size_t)ET * 128 * 2);
  // total ws ≈ 360 MB

  // dtype flag, then f32 weight mirrors
  k_sniff<<<1, 256, 0, stream>>>((const u32*)G_ef, flag);
  auto cvt = [&](int idx, float* dst, int n){
    k_cvtw<<<(n + 255) / 256, 256, 0, stream>>>(d_in[idx], dst, n, flag);
  };
  cvt(12, wmW1, 8192);  cvt(13, wmW2, 8192);  cvt(14, wmW3, 16384);
  cvt(15, wmU1G, 8192); cvt(16, wmU2G, 16384);
  cvt(17, wmWz, 16384); cvt(18, wmUz, 16384);
  cvt(19, wmWr, 16384); cvt(20, wmUr, 16384);
  cvt(21, wmWh, 16384); cvt(22, wmUh, 16384);
  cvt(23, wmU1T, 16384); cvt(24, wmU2T, 16384);

  auto build = [&](const int* dst, const int* src, int ne, int nseg, int* rp, int* col){
    hipMemsetAsync(cnt, 0, sizeof(int) * 2 * nseg, stream);
    k_hist<<<(ne + 255) / 256, 256, 0, stream>>>(dst, ne, cnt);
    int nch = (nseg + 4095) / 4096;
    k_scan1<<<nch, 256, 0, stream>>>(cnt, nseg, csum);
    k_scan2<<<1, 64, 0, stream>>>(csum, nch, rp, nseg);
    k_scan3<<<nch, 256, 0, stream>>>(cnt, nseg, csum, rp);
    k_fill<<<(ne + 255) / 256, 256, 0, stream>>>(dst, src, ne, rp, cnt + nseg, col);
  };
  build(G_lg_dst, G_lg_src, ELG, EG, rpG, colG);
  build(G_dst, nullptr, EG, NG, rpGd, colGd);
  build(T_lg_dst, T_lg_src, ELGT, ET, rpT, colT);
  build(T_dst, nullptr, ET, NT, rpTd, colTd);

  int gEG = (EG + 63) / 64, gNG = (NG + 63) / 64, gET = (ET + 63) / 64, gNT = (NT + 63) / 64;

  // ---- molecule graph G ----
  k_baseG<<<gEG, 256, 0, stream>>>(G_f, G_ef, G_src, wmW1, wmW2, flag, msgGA, EG);
  k_iterG<<<gEG, 256, 0, stream>>>(msgGA, msgGB, G_f, G_ef, G_src, rpG, colG, wmW1, wmW2, wmW3, flag, EG);
  k_iterG<<<gEG, 256, 0, stream>>>(msgGB, msgGA, G_f, G_ef, G_src, rpG, colG, wmW1, wmW2, wmW3, flag, EG);
  k_iterG<<<gEG, 256, 0, stream>>>(msgGA, msgGB, G_f, G_ef, G_src, rpG, colG, wmW1, wmW2, wmW3, flag, EG);
  k_readoutG<<<gNG, 256, 0, stream>>>(G_f, msgGB, rpGd, colGd, wmU1G, wmU2G, flag, out, NG);

  // ---- junction tree T ----
  k_fT<<<(NT * 16 + 255) / 256, 256, 0, stream>>>(T_id, emb, flag, fT);
  k_xzrh<<<gET, 256, 0, stream>>>(fT, T_src, wmWz, wmWr, wmWh, xzrh, msgTA, ET);
  k_iterT<<<gET, 256, 0, stream>>>(msgTA, xzrh, msgTB, rpT, colT, wmUz, wmUr, wmUh, ET);
  k_iterT<<<gET, 256, 0, stream>>>(msgTB, xzrh, msgTA, rpT, colT, wmUz, wmUr, wmUh, ET);
  k_iterT<<<gET, 256, 0, stream>>>(msgTA, xzrh, msgTB, rpT, colT, wmUz, wmUr, wmUh, ET);
  k_readoutT<<<gNT, 256, 0, stream>>>(fT, msgTB, rpTd, colTd, wmU1T, wmU2T, out + (size_t)NG * 128, NT);
}

// Round 3
// 1505.140 us; speedup vs baseline: 1.8291x; 1.8291x over previous
//
#include <hip/hip_runtime.h>

#define NG 100000
#define EG 400000
#define ELG 1200000
#define NT 50000
#define ET 100000
#define ELGT 300000

typedef unsigned short u16;
typedef unsigned int u32;
typedef __attribute__((ext_vector_type(8))) short bf16x8;
typedef __attribute__((ext_vector_type(4))) float f32x4;

#define TILE_BYTES (64 * 256)

__device__ __forceinline__ float bflo(u32 p){ return __uint_as_float(p << 16); }
__device__ __forceinline__ float bfhi(u32 p){ return __uint_as_float(p & 0xffff0000u); }
__device__ __forceinline__ float bf2f(u16 h){ return __uint_as_float(((u32)h) << 16); }
__device__ __forceinline__ u16 f2bf(float f){
  u32 u = __float_as_uint(f);
  u32 r = u + 0x7fffu + ((u >> 16) & 1u);
  return (u16)(r >> 16);
}
__device__ __forceinline__ float sigm(float x){ return 1.0f / (1.0f + __expf(-x)); }
__device__ __forceinline__ float tanh_(float x){ return 2.0f / (1.0f + __expf(-2.0f * x)) - 1.0f; }
__device__ __forceinline__ float relu_(float x){ return x > 0.0f ? x : 0.0f; }

// LDS tile byte swizzle: row stride 256B, XOR row bits into byte bits 4-6 (T2)
__device__ __forceinline__ int swz(int r, int c){ return r * 256 + (c ^ ((r & 7) << 4)); }

__device__ __forceinline__ void zero8(float v[8]){
  #pragma unroll
  for (int j = 0; j < 8; j++) v[j] = 0.f;
}
__device__ __forceinline__ uint4 pack8(const float v[8]){
  uint4 o;
  o.x = f2bf(v[0]) | ((u32)f2bf(v[1]) << 16);
  o.y = f2bf(v[2]) | ((u32)f2bf(v[3]) << 16);
  o.z = f2bf(v[4]) | ((u32)f2bf(v[5]) << 16);
  o.w = f2bf(v[6]) | ((u32)f2bf(v[7]) << 16);
  return o;
}

// ---------------- dtype sniffer (bf16 vs f32 inputs) ----------------
__global__ void k_sniff(const u32* __restrict__ g, int* __restrict__ flag){
  __shared__ int sh[2];
  if (threadIdx.x < 2) sh[threadIdx.x] = 0;
  __syncthreads();
  int c0 = 0, c1 = 0;
  for (int i = 0; i < 16; i++){
    u32 w = g[threadIdx.x * 16 + i];
    u32 lo = w & 0xFFFFu;
    if (lo == 0u) c0++;
    else { u32 e = (lo >> 7) & 0xFFu; if (e >= 96u && e <= 144u) c1++; }
  }
  atomicAdd(&sh[0], c0); atomicAdd(&sh[1], c1);
  __syncthreads();
  if (threadIdx.x == 0) *flag = (sh[0] < 512 && sh[1] > 2048) ? 1 : 0;
}

__global__ void k_cvtw(const void* __restrict__ src, float* __restrict__ dst, int n,
                       const int* __restrict__ flagp){
  int i = blockIdx.x * 256 + threadIdx.x;
  if (i >= n) return;
  if (*flagp) dst[i] = bf2f(((const u16*)src)[i]);
  else        dst[i] = ((const float*)src)[i];
}

// build MFMA B-fragment table from f32 weight (K x 128):
// frag[ks][nt][lane][j] = W[ks*32 + (lane>>4)*8 + j][nt*16 + (lane&15)]
__global__ void k_mkfrag(const float* __restrict__ W, u16* __restrict__ frag){
  int ks = blockIdx.x;
  int nt = threadIdx.x >> 6, lane = threadIdx.x & 63;
  int kr = ks * 32 + ((lane >> 4) << 3);
  int col = nt * 16 + (lane & 15);
  u16* o = frag + (size_t)ks * 4096 + nt * 512 + lane * 8;
  #pragma unroll
  for (int j = 0; j < 8; j++) o[j] = f2bf(W[(size_t)(kr + j) * 128 + col]);
}

// ---------------- dual-dtype row access ----------------
__device__ __forceinline__ const void* rowdt(const void* mat, size_t row, int W, int bf){
  return bf ? (const void*)((const u16*)mat + row * (size_t)W)
            : (const void*)((const float*)mat + row * (size_t)W);
}
__device__ __forceinline__ void load8(const void* rowbase, int c8, int bf, float v[8]){
  if (bf){
    uint4 d = ((const uint4*)rowbase)[c8];
    v[0]=bflo(d.x); v[1]=bfhi(d.x); v[2]=bflo(d.y); v[3]=bfhi(d.y);
    v[4]=bflo(d.z); v[5]=bfhi(d.z); v[6]=bflo(d.w); v[7]=bfhi(d.w);
  } else {
    const float4* p = (const float4*)rowbase + (c8 << 1);
    float4 a = p[0], b = p[1];
    v[0]=a.x; v[1]=a.y; v[2]=a.z; v[3]=a.w; v[4]=b.x; v[5]=b.y; v[6]=b.z; v[7]=b.w;
  }
}

// ---------------- CSR build ----------------
__global__ void k_hist(const int* __restrict__ dst, int ne, int* __restrict__ cnt){
  int e = blockIdx.x * 256 + threadIdx.x;
  if (e < ne) atomicAdd(&cnt[dst[e]], 1);
}

__global__ void k_scan1(const int* __restrict__ cnt, int n, int* __restrict__ csum){
  int base = blockIdx.x * 4096, tid = threadIdx.x;
  int s = 0;
  for (int i = 0; i < 16; i++){ int idx = base + i * 256 + tid; if (idx < n) s += cnt[idx]; }
  __shared__ int red[4];
  for (int off = 32; off; off >>= 1) s += __shfl_down(s, off, 64);
  if ((tid & 63) == 0) red[tid >> 6] = s;
  __syncthreads();
  if (tid == 0) csum[blockIdx.x] = red[0] + red[1] + red[2] + red[3];
}

__global__ void k_scan2(int* csum, int nch, int* rowptr, int n){
  if (threadIdx.x == 0){
    int run = 0;
    for (int c = 0; c < nch; c++){ int t = csum[c]; csum[c] = run; run += t; }
    rowptr[n] = run;
  }
}

__global__ void k_scan3(const int* __restrict__ cnt, int n, const int* __restrict__ csum,
                        int* __restrict__ rowptr){
  __shared__ int buf[4096];
  __shared__ int tsum[256];
  int base = blockIdx.x * 4096, tid = threadIdx.x;
  for (int i = 0; i < 16; i++){ int idx = base + i * 256 + tid; buf[i * 256 + tid] = (idx < n) ? cnt[idx] : 0; }
  __syncthreads();
  int run = 0;
  for (int i = 0; i < 16; i++){ int v = buf[tid * 16 + i]; buf[tid * 16 + i] = run; run += v; }
  tsum[tid] = run;
  __syncthreads();
  for (int off = 1; off < 256; off <<= 1){
    int v = (tid >= off) ? tsum[tid - off] : 0;
    __syncthreads();
    tsum[tid] += v;
    __syncthreads();
  }
  int texcl = tsum[tid] - run;
  int cbase = csum[blockIdx.x];
  for (int i = 0; i < 16; i++){
    int idx = base + tid * 16 + i;
    if (idx < n) rowptr[idx] = cbase + texcl + buf[tid * 16 + i];
  }
}

__global__ void k_fill(const int* __restrict__ dst, const int* __restrict__ src, int ne,
                       const int* __restrict__ rowptr, int* __restrict__ fillcnt, int* __restrict__ col){
  int e = blockIdx.x * 256 + threadIdx.x;
  if (e >= ne) return;
  int d = dst[e];
  int pos = atomicAdd(&fillcnt[d], 1);
  col[rowptr[d] + pos] = src ? src[e] : e;
}

// ---------------- tile staging (256 threads, 64-row tiles, bf16 swizzled) ----------------

// CSR gather-sum of bf16 msg rows -> bf16 swizzled tile
__device__ __forceinline__ void gather_tile(char* __restrict__ tile,
    const int* __restrict__ rowptr, const int* __restrict__ colidx,
    const u16* __restrict__ msg, int row0, int M)
{
  int tid = threadIdx.x;
  int rl = tid >> 2, q = tid & 3;
  int row = row0 + rl;
  float acc[4][8];
  #pragma unroll
  for (int v = 0; v < 4; v++) zero8(acc[v]);
  if (row < M){
    int p = rowptr[row], pe = rowptr[row + 1];
    for (; p < pe; ++p){
      int sr = colidx[p];
      const uint4* b = (const uint4*)(msg + (size_t)sr * 128);
      #pragma unroll
      for (int v = 0; v < 4; v++){
        uint4 d = b[v * 4 + q];
        acc[v][0] += bflo(d.x); acc[v][1] += bfhi(d.x);
        acc[v][2] += bflo(d.y); acc[v][3] += bfhi(d.y);
        acc[v][4] += bflo(d.z); acc[v][5] += bfhi(d.z);
        acc[v][6] += bflo(d.w); acc[v][7] += bfhi(d.w);
      }
    }
  }
  #pragma unroll
  for (int v = 0; v < 4; v++)
    *(uint4*)(tile + swz(rl, (v * 4 + q) * 16)) = pack8(acc[v]);
}

// concat(Gf[Gsrc], Gef) 64+64 cols -> tile (dual-dtype source)
__device__ __forceinline__ void stage_cat_tile(char* __restrict__ tile,
    const void* __restrict__ Gf, const void* __restrict__ Gef,
    const int* __restrict__ Gsrc, int row0, int M, int bf)
{
  int tid = threadIdx.x, rl = tid >> 2, q = tid & 3;
  int row = row0 + rl;
  float A0[8], A1[8], B0[8], B1[8];
  if (row < M){
    int sr = Gsrc[row];
    const void* ra = rowdt(Gf, (size_t)sr, 64, bf);
    const void* rb = rowdt(Gef, (size_t)row, 64, bf);
    load8(ra, q, bf, A0); load8(ra, q + 4, bf, A1);
    load8(rb, q, bf, B0); load8(rb, q + 4, bf, B1);
  } else { zero8(A0); zero8(A1); zero8(B0); zero8(B1); }
  *(uint4*)(tile + swz(rl, q * 16))            = pack8(A0);
  *(uint4*)(tile + swz(rl, (q + 4) * 16))      = pack8(A1);
  *(uint4*)(tile + swz(rl, 128 + q * 16))      = pack8(B0);
  *(uint4*)(tile + swz(rl, 128 + (q + 4) * 16))= pack8(B1);
}

// 64-wide dual-dtype rows -> tile cols 0-63 (K=64)
__device__ __forceinline__ void stage_w64_tile(char* __restrict__ tile,
    const void* __restrict__ mat, int row0, int M, int bf)
{
  int tid = threadIdx.x, rl = tid >> 2, q = tid & 3;
  int row = row0 + rl;
  float A0[8], A1[8];
  if (row < M){
    const void* ra = rowdt(mat, (size_t)row, 64, bf);
    load8(ra, q, bf, A0); load8(ra, q + 4, bf, A1);
  } else { zero8(A0); zero8(A1); }
  *(uint4*)(tile + swz(rl, q * 16))       = pack8(A0);
  *(uint4*)(tile + swz(rl, (q + 4) * 16)) = pack8(A1);
}

// bf16 ws rows (optionally indexed) -> tile (raw copy)
__device__ __forceinline__ void stage_bf16_tile(char* __restrict__ tile,
    const u16* __restrict__ mat, const int* __restrict__ idx, int row0, int M)
{
  int tid = threadIdx.x, rl = tid >> 2, q = tid & 3;
  int row = row0 + rl;
  if (row < M){
    int sr = idx ? idx[row] : row;
    const uint4* b = (const uint4*)(mat + (size_t)sr * 128);
    #pragma unroll
    for (int v = 0; v < 4; v++)
      *(uint4*)(tile + swz(rl, (v * 4 + q) * 16)) = b[v * 4 + q];
  } else {
    uint4 z = make_uint4(0, 0, 0, 0);
    #pragma unroll
    for (int v = 0; v < 4; v++)
      *(uint4*)(tile + swz(rl, (v * 4 + q) * 16)) = z;
  }
}

// acc[nt] += A_tile(stripe rows, K=32*ksteps) @ Wfrag
__device__ __forceinline__ void mma_acc(const char* __restrict__ tile, int stripe,
    const u16* __restrict__ frag, int ksteps, f32x4 (&acc)[8])
{
  int lane = threadIdx.x & 63;
  int ar = stripe + (lane & 15);
  int acb = (lane >> 4) << 4;
  for (int ks = 0; ks < ksteps; ks++){
    bf16x8 a = *(const bf16x8*)(tile + swz(ar, ks * 64 + acb));
    const u16* fb = frag + (size_t)ks * 4096 + lane * 8;
    #pragma unroll
    for (int nt = 0; nt < 8; nt++){
      bf16x8 b = *(const bf16x8*)(fb + (size_t)nt * 512);
      acc[nt] = __builtin_amdgcn_mfma_f32_16x16x32_bf16(a, b, acc[nt], 0, 0, 0);
    }
  }
}

#define INIT_ACC(A) { _Pragma("unroll") for (int n_=0;n_<8;n_++){ A[n_][0]=0.f; A[n_][1]=0.f; A[n_][2]=0.f; A[n_][3]=0.f; } }

// repack tile (bf16, swizzled) -> row-major global bf16
__device__ __forceinline__ void repack_store(const char* __restrict__ tile,
    u16* __restrict__ dst, int row0, int M)
{
  int rl = threadIdx.x >> 2, q = threadIdx.x & 3;
  int grow = row0 + rl;
  if (grow < M){
    #pragma unroll
    for (int v = 0; v < 4; v++){
      uint4 d = *(const uint4*)(tile + swz(rl, (v * 4 + q) * 16));
      *(uint4*)(dst + (size_t)grow * 128 + (size_t)(v * 4 + q) * 8) = d;
    }
  }
}

// ---------------- pipeline kernels (MFMA) ----------------

// msg1 = relu(Gf[Gsrc]@W1 + Gef@W2)
__global__ __launch_bounds__(256) void k_baseG(const void* __restrict__ Gf, const void* __restrict__ Gef,
    const int* __restrict__ Gsrc, const u16* __restrict__ fWcat,
    const int* __restrict__ flagp, u16* __restrict__ msg, int M)
{
  __shared__ char t0[TILE_BYTES];
  int bf = *flagp;
  int row0 = blockIdx.x * 64;
  stage_cat_tile(t0, Gf, Gef, Gsrc, row0, M, bf);
  __syncthreads();
  int w = threadIdx.x >> 6, lane = threadIdx.x & 63, stripe = w * 16;
  f32x4 acc[8]; INIT_ACC(acc);
  mma_acc(t0, stripe, fWcat, 4, acc);
  #pragma unroll
  for (int nt = 0; nt < 8; nt++)
    #pragma unroll
    for (int r = 0; r < 4; r++){
      int rt = stripe + ((lane >> 4) << 2) + r;
      int cb = nt * 32 + (lane & 15) * 2;
      *(u16*)(t0 + swz(rt, cb)) = f2bf(relu_(acc[nt][r]));
    }
  __syncthreads();
  repack_store(t0, msg, row0, M);
}

// msg_out = relu( Gf[Gsrc]@W1 + Gef@W2 + segsum(msg_in)@W3 )
__global__ __launch_bounds__(256) void k_iterG(const u16* __restrict__ msg_in, u16* __restrict__ msg_out,
    const void* __restrict__ Gf, const void* __restrict__ Gef, const int* __restrict__ Gsrc,
    const int* __restrict__ rowptr, const int* __restrict__ colidx,
    const u16* __restrict__ fWcat, const u16* __restrict__ fW3,
    const int* __restrict__ flagp, int M)
{
  __shared__ char t0[TILE_BYTES];
  __shared__ char t1[TILE_BYTES];
  int bf = *flagp;
  int row0 = blockIdx.x * 64;
  stage_cat_tile(t0, Gf, Gef, Gsrc, row0, M, bf);
  gather_tile(t1, rowptr, colidx, msg_in, row0, M);
  __syncthreads();
  int w = threadIdx.x >> 6, lane = threadIdx.x & 63, stripe = w * 16;
  f32x4 acc[8]; INIT_ACC(acc);
  mma_acc(t0, stripe, fWcat, 4, acc);
  mma_acc(t1, stripe, fW3, 4, acc);
  #pragma unroll
  for (int nt = 0; nt < 8; nt++)
    #pragma unroll
    for (int r = 0; r < 4; r++){
      int rt = stripe + ((lane >> 4) << 2) + r;
      int cb = nt * 32 + (lane & 15) * 2;
      *(u16*)(t1 + swz(rt, cb)) = f2bf(relu_(acc[nt][r]));
    }
  __syncthreads();
  repack_store(t1, msg_out, row0, M);
}

// out = relu(Gf@U1 + segsum_dst(msg)@U2)   (f32 output)
__global__ __launch_bounds__(256) void k_readoutG(const void* __restrict__ Gf,
    const u16* __restrict__ msg, const int* __restrict__ rowptr, const int* __restrict__ colidx,
    const u16* __restrict__ fU1, const u16* __restrict__ fU2,
    const int* __restrict__ flagp, float* __restrict__ out, int M)
{
  __shared__ char t0[TILE_BYTES];
  __shared__ char t1[TILE_BYTES];
  int bf = *flagp;
  int row0 = blockIdx.x * 64;
  stage_w64_tile(t0, Gf, row0, M, bf);
  gather_tile(t1, rowptr, colidx, msg, row0, M);
  __syncthreads();
  int w = threadIdx.x >> 6, lane = threadIdx.x & 63, stripe = w * 16;
  f32x4 acc[8]; INIT_ACC(acc);
  mma_acc(t0, stripe, fU1, 2, acc);
  mma_acc(t1, stripe, fU2, 4, acc);
  #pragma unroll
  for (int nt = 0; nt < 8; nt++)
    #pragma unroll
    for (int r = 0; r < 4; r++){
      int R = row0 + stripe + ((lane >> 4) << 2) + r;
      if (R < M) out[(size_t)R * 128 + nt * 16 + (lane & 15)] = relu_(acc[nt][r]);
    }
}

// f_T = embeddings[T_id]  (bf16 ws)
__global__ void k_fT(const int* __restrict__ Tid, const void* __restrict__ emb,
                     const int* __restrict__ flagp, u16* __restrict__ fT){
  int g = blockIdx.x * 256 + threadIdx.x;
  if (g >= NT * 16) return;
  int bf = *flagp;
  int n = g >> 4, c8 = g & 15;
  const void* rb = rowdt(emb, (size_t)Tid[n], 128, bf);
  float t[8]; load8(rb, c8, bf, t);
  *(uint4*)(fT + (size_t)n * 128 + c8 * 8) = pack8(t);
}

// frag-major index for xz/xr/xh intermediates
__device__ __forceinline__ size_t fidx(int blk, int w, int nt, int r, int lane){
  return ((((size_t)blk * 4 + w) * 8 + nt) * 4 + r) * 64 + lane;
}

// xz/xr/xh = f_T[T_src]@{Wz,Wr,Wh} (frag-major bf16); msg1 = sigmoid(xz)*tanh(xh)
__global__ __launch_bounds__(256) void k_xzrh(const u16* __restrict__ fT, const int* __restrict__ Tsrc,
    const u16* __restrict__ fWz, const u16* __restrict__ fWr, const u16* __restrict__ fWh,
    u16* __restrict__ xzf, u16* __restrict__ xrf, u16* __restrict__ xhf,
    u16* __restrict__ msg, int M)
{
  __shared__ char t0[TILE_BYTES];
  int row0 = blockIdx.x * 64;
  stage_bf16_tile(t0, fT, Tsrc, row0, M);
  __syncthreads();
  int w = threadIdx.x >> 6, lane = threadIdx.x & 63, stripe = w * 16;
  f32x4 aZ[8]; INIT_ACC(aZ);
  mma_acc(t0, stripe, fWz, 4, aZ);
  {
    f32x4 aR[8]; INIT_ACC(aR);
    mma_acc(t0, stripe, fWr, 4, aR);
    #pragma unroll
    for (int nt = 0; nt < 8; nt++)
      #pragma unroll
      for (int r = 0; r < 4; r++)
        xrf[fidx(blockIdx.x, w, nt, r, lane)] = f2bf(aR[nt][r]);
  }
  f32x4 aH[8]; INIT_ACC(aH);
  mma_acc(t0, stripe, fWh, 4, aH);
  #pragma unroll
  for (int nt = 0; nt < 8; nt++)
    #pragma unroll
    for (int r = 0; r < 4; r++){
      size_t fi = fidx(blockIdx.x, w, nt, r, lane);
      xzf[fi] = f2bf(aZ[nt][r]);
      xhf[fi] = f2bf(aH[nt][r]);
      int rt = stripe + ((lane >> 4) << 2) + r;
      int cb = nt * 32 + (lane & 15) * 2;
      *(u16*)(t0 + swz(rt, cb)) = f2bf(sigm(aZ[nt][r]) * tanh_(aH[nt][r]));
    }
  __syncthreads();
  repack_store(t0, msg, row0, M);
}

// GRU step: s=segsum(msg); z=sig(xz+s@Uz); r=sig(xr+s@Ur); h=tanh(xh+(r*s)@Uh); msg=(1-z)s+zh
__global__ __launch_bounds__(256) void k_iterT(const u16* __restrict__ msg_in, u16* __restrict__ msg_out,
    const int* __restrict__ rowptr, const int* __restrict__ colidx,
    const u16* __restrict__ fUz, const u16* __restrict__ fUr, const u16* __restrict__ fUh,
    const u16* __restrict__ xzf, const u16* __restrict__ xrf, const u16* __restrict__ xhf, int M)
{
  __shared__ char t0[TILE_BYTES];
  __shared__ char t1[TILE_BYTES];
  int row0 = blockIdx.x * 64;
  gather_tile(t0, rowptr, colidx, msg_in, row0, M);
  __syncthreads();
  int w = threadIdx.x >> 6, lane = threadIdx.x & 63, stripe = w * 16;
  f32x4 aZ[8], aR[8];
  INIT_ACC(aZ); INIT_ACC(aR);
  mma_acc(t0, stripe, fUz, 4, aZ);
  mma_acc(t0, stripe, fUr, 4, aR);
  float zz[8][4];
  #pragma unroll
  for (int nt = 0; nt < 8; nt++)
    #pragma unroll
    for (int r = 0; r < 4; r++){
      int rt = stripe + ((lane >> 4) << 2) + r;
      int cb = nt * 32 + (lane & 15) * 2;
      float s = bf2f(*(const u16*)(t0 + swz(rt, cb)));
      size_t fi = fidx(blockIdx.x, w, nt, r, lane);
      float z = sigm(bf2f(xzf[fi]) + aZ[nt][r]);
      float rr = sigm(bf2f(xrf[fi]) + aR[nt][r]);
      zz[nt][r] = z;
      *(u16*)(t1 + swz(rt, cb)) = f2bf(rr * s);
    }
  __syncthreads();
  f32x4 aH[8]; INIT_ACC(aH);
  mma_acc(t1, stripe, fUh, 4, aH);
  #pragma unroll
  for (int nt = 0; nt < 8; nt++)
    #pragma unroll
    for (int r = 0; r < 4; r++){
      int rt = stripe + ((lane >> 4) << 2) + r;
      int cb = nt * 32 + (lane & 15) * 2;
      float s = bf2f(*(const u16*)(t0 + swz(rt, cb)));
      size_t fi = fidx(blockIdx.x, w, nt, r, lane);
      float h = tanh_(bf2f(xhf[fi]) + aH[nt][r]);
      float m = (1.f - zz[nt][r]) * s + zz[nt][r] * h;
      *(u16*)(t0 + swz(rt, cb)) = f2bf(m);
    }
  __syncthreads();
  repack_store(t0, msg_out, row0, M);
}

// out = relu(f_T@U1 + segsum_dst(msg)@U2)   (f32 output)
__global__ __launch_bounds__(256) void k_readoutT(const u16* __restrict__ fT,
    const u16* __restrict__ msg, const int* __restrict__ rowptr, const int* __restrict__ colidx,
    const u16* __restrict__ fU1, const u16* __restrict__ fU2, float* __restrict__ out, int M)
{
  __shared__ char t0[TILE_BYTES];
  __shared__ char t1[TILE_BYTES];
  int row0 = blockIdx.x * 64;
  stage_bf16_tile(t0, fT, nullptr, row0, M);
  gather_tile(t1, rowptr, colidx, msg, row0, M);
  __syncthreads();
  int w = threadIdx.x >> 6, lane = threadIdx.x & 63, stripe = w * 16;
  f32x4 acc[8]; INIT_ACC(acc);
  mma_acc(t0, stripe, fU1, 4, acc);
  mma_acc(t1, stripe, fU2, 4, acc);
  #pragma unroll
  for (int nt = 0; nt < 8; nt++)
    #pragma unroll
    for (int r = 0; r < 4; r++){
      int R = row0 + stripe + ((lane >> 4) << 2) + r;
      if (R < M) out[(size_t)R * 128 + nt * 16 + (lane & 15)] = relu_(acc[nt][r]);
    }
}

// ---------------- host launcher ----------------
extern "C" void kernel_launch(void* const* d_in, const int* in_sizes, int n_in,
                              void* d_out, int out_size, void* d_ws, size_t ws_size,
                              hipStream_t stream)
{
  const void* G_f      = d_in[0];
  const void* G_ef     = d_in[1];
  const int*  G_src    = (const int*)d_in[2];
  const int*  G_dst    = (const int*)d_in[3];
  const int*  G_lg_src = (const int*)d_in[4];
  const int*  G_lg_dst = (const int*)d_in[5];
  const int*  T_id     = (const int*)d_in[6];
  const int*  T_src    = (const int*)d_in[7];
  const int*  T_dst    = (const int*)d_in[8];
  const int*  T_lg_src = (const int*)d_in[9];
  const int*  T_lg_dst = (const int*)d_in[10];
  const void* emb      = d_in[11];
  float* out = (float*)d_out;
  (void)in_sizes; (void)n_in; (void)out_size; (void)ws_size;

  size_t off = 0;
  auto alloc = [&](size_t bytes) -> char* {
    char* p = (char*)d_ws + off;
    off += (bytes + 255) & ~(size_t)255;
    return p;
  };

  int gEG = (EG + 63) / 64, gNG = (NG + 63) / 64, gET = (ET + 63) / 64, gNT = (NT + 63) / 64;

  int*   flag = (int*)alloc(256);
  float* wm   = (float*)alloc(sizeof(float) * 188416);   // f32 weight mirrors
  float* wmW1  = wm;
  float* wmW2  = wm + 8192;
  float* wmW3  = wm + 16384;
  float* wmU1G = wm + 32768;
  float* wmU2G = wm + 40960;
  float* wmWz  = wm + 57344;
  float* wmUz  = wm + 73728;
  float* wmWr  = wm + 90112;
  float* wmUr  = wm + 106496;
  float* wmWh  = wm + 122880;
  float* wmUh  = wm + 139264;
  float* wmU1T = wm + 155648;
  float* wmU2T = wm + 172032;

  // MFMA B-fragment tables (bf16)
  u16* fWcat = (u16*)alloc(2 * 16384);
  u16* fW3   = (u16*)alloc(2 * 16384);
  u16* fU1G  = (u16*)alloc(2 * 8192);
  u16* fU2G  = (u16*)alloc(2 * 16384);
  u16* fWz   = (u16*)alloc(2 * 16384);
  u16* fWr   = (u16*)alloc(2 * 16384);
  u16* fWh   = (u16*)alloc(2 * 16384);
  u16* fUz   = (u16*)alloc(2 * 16384);
  u16* fUr   = (u16*)alloc(2 * 16384);
  u16* fUh   = (u16*)alloc(2 * 16384);
  u16* fU1T  = (u16*)alloc(2 * 16384);
  u16* fU2T  = (u16*)alloc(2 * 16384);

  int* rpG   = (int*)alloc(sizeof(int) * (EG + 1));
  int* colG  = (int*)alloc(sizeof(int) * ELG);
  int* rpGd  = (int*)alloc(sizeof(int) * (NG + 1));
  int* colGd = (int*)alloc(sizeof(int) * EG);
  int* rpT   = (int*)alloc(sizeof(int) * (ET + 1));
  int* colT  = (int*)alloc(sizeof(int) * ELGT);
  int* rpTd  = (int*)alloc(sizeof(int) * (NT + 1));
  int* colTd = (int*)alloc(sizeof(int) * ET);
  int* cnt   = (int*)alloc(sizeof(int) * 2 * EG);
  int* csum  = (int*)alloc(sizeof(int) * 128);
  u16* msgGA = (u16*)alloc((size_t)EG * 128 * 2);
  u16* msgGB = (u16*)alloc((size_t)EG * 128 * 2);
  u16* fT    = (u16*)alloc((size_t)NT * 128 * 2);
  u16* xzf   = (u16*)alloc((size_t)gET * 8192 * 2);
  u16* xrf   = (u16*)alloc((size_t)gET * 8192 * 2);
  u16* xhf   = (u16*)alloc((size_t)gET * 8192 * 2);
  u16* msgTA = (u16*)alloc((size_t)ET * 128 * 2);
  u16* msgTB = (u16*)alloc((size_t)ET * 128 * 2);

  // dtype flag -> f32 weight mirrors -> fragment tables
  k_sniff<<<1, 256, 0, stream>>>((const u32*)G_ef, flag);
  auto cvt = [&](int idx, float* dst, int n){
    k_cvtw<<<(n + 255) / 256, 256, 0, stream>>>(d_in[idx], dst, n, flag);
  };
  cvt(12, wmW1, 8192);  cvt(13, wmW2, 8192);  cvt(14, wmW3, 16384);
  cvt(15, wmU1G, 8192); cvt(16, wmU2G, 16384);
  cvt(17, wmWz, 16384); cvt(18, wmUz, 16384);
  cvt(19, wmWr, 16384); cvt(20, wmUr, 16384);
  cvt(21, wmWh, 16384); cvt(22, wmUh, 16384);
  cvt(23, wmU1T, 16384); cvt(24, wmU2T, 16384);

  k_mkfrag<<<2, 512, 0, stream>>>(wmW1, fWcat);
  k_mkfrag<<<2, 512, 0, stream>>>(wmW2, fWcat + 2 * 4096);
  k_mkfrag<<<4, 512, 0, stream>>>(wmW3, fW3);
  k_mkfrag<<<2, 512, 0, stream>>>(wmU1G, fU1G);
  k_mkfrag<<<4, 512, 0, stream>>>(wmU2G, fU2G);
  k_mkfrag<<<4, 512, 0, stream>>>(wmWz, fWz);
  k_mkfrag<<<4, 512, 0, stream>>>(wmWr, fWr);
  k_mkfrag<<<4, 512, 0, stream>>>(wmWh, fWh);
  k_mkfrag<<<4, 512, 0, stream>>>(wmUz, fUz);
  k_mkfrag<<<4, 512, 0, stream>>>(wmUr, fUr);
  k_mkfrag<<<4, 512, 0, stream>>>(wmUh, fUh);
  k_mkfrag<<<4, 512, 0, stream>>>(wmU1T, fU1T);
  k_mkfrag<<<4, 512, 0, stream>>>(wmU2T, fU2T);

  auto build = [&](const int* dst, const int* src, int ne, int nseg, int* rp, int* col){
    hipMemsetAsync(cnt, 0, sizeof(int) * 2 * nseg, stream);
    k_hist<<<(ne + 255) / 256, 256, 0, stream>>>(dst, ne, cnt);
    int nch = (nseg + 4095) / 4096;
    k_scan1<<<nch, 256, 0, stream>>>(cnt, nseg, csum);
    k_scan2<<<1, 64, 0, stream>>>(csum, nch, rp, nseg);
    k_scan3<<<nch, 256, 0, stream>>>(cnt, nseg, csum, rp);
    k_fill<<<(ne + 255) / 256, 256, 0, stream>>>(dst, src, ne, rp, cnt + nseg, col);
  };
  build(G_lg_dst, G_lg_src, ELG, EG, rpG, colG);
  build(G_dst, nullptr, EG, NG, rpGd, colGd);
  build(T_lg_dst, T_lg_src, ELGT, ET, rpT, colT);
  build(T_dst, nullptr, ET, NT, rpTd, colTd);

  // ---- molecule graph G ----
  k_baseG<<<gEG, 256, 0, stream>>>(G_f, G_ef, G_src, fWcat, flag, msgGA, EG);
  k_iterG<<<gEG, 256, 0, stream>>>(msgGA, msgGB, G_f, G_ef, G_src, rpG, colG, fWcat, fW3, flag, EG);
  k_iterG<<<gEG, 256, 0, stream>>>(msgGB, msgGA, G_f, G_ef, G_src, rpG, colG, fWcat, fW3, flag, EG);
  k_iterG<<<gEG, 256, 0, stream>>>(msgGA, msgGB, G_f, G_ef, G_src, rpG, colG, fWcat, fW3, flag, EG);
  k_readoutG<<<gNG, 256, 0, stream>>>(G_f, msgGB, rpGd, colGd, fU1G, fU2G, flag, out, NG);

  // ---- junction tree T ----
  k_fT<<<(NT * 16 + 255) / 256, 256, 0, stream>>>(T_id, emb, flag, fT);
  k_xzrh<<<gET, 256, 0, stream>>>(fT, T_src, fWz, fWr, fWh, xzf, xrf, xhf, msgTA, ET);
  k_iterT<<<gET, 256, 0, stream>>>(msgTA, msgTB, rpT, colT, fUz, fUr, fUh, xzf, xrf, xhf, ET);
  k_iterT<<<gET, 256, 0, stream>>>(msgTB, msgTA, rpT, colT, fUz, fUr, fUh, xzf, xrf, xhf, ET);
  k_iterT<<<gET, 256, 0, stream>>>(msgTA, msgTB, rpT, colT, fUz, fUr, fUh, xzf, xrf, xhf, ET);
  k_readoutT<<<gNT, 256, 0, stream>>>(fT, msgTB, rpTd, colTd, fU1T, fU2T, out + (size_t)NG * 128, NT);
}

// Round 4
// 1350.632 us; speedup vs baseline: 2.0383x; 1.1144x over previous
//
#include <hip/hip_runtime.h>

#define NG 100000
#define EG 400000
#define ELG 1200000
#define NT 50000
#define ET 100000
#define ELGT 300000

#define GEG ((EG + 63) / 64)     // 6250
#define GET ((ET + 63) / 64)     // 1563
#define GNG ((NG + 63) / 64)     // 1563
#define GNT ((NT + 63) / 64)     // 782

// concatenated CSR segment space: [G_lg(EG) | G_dst(NG) | T_lg(ET) | T_dst(NT)]
#define SEG1 EG
#define SEG2 (EG + NG)
#define SEG3 (EG + NG + ET)
#define NSEG_ALL (EG + NG + ET + NT)
#define NE_ALL (ELG + EG + ELGT + ET)

typedef unsigned short u16;
typedef unsigned int u32;
typedef __attribute__((ext_vector_type(8))) short bf16x8;
typedef __attribute__((ext_vector_type(4))) float f32x4;

#define TILE_BYTES (64 * 256)

__device__ __forceinline__ float bflo(u32 p){ return __uint_as_float(p << 16); }
__device__ __forceinline__ float bfhi(u32 p){ return __uint_as_float(p & 0xffff0000u); }
__device__ __forceinline__ float bf2f(u16 h){ return __uint_as_float(((u32)h) << 16); }
__device__ __forceinline__ u16 f2bf(float f){
  u32 u = __float_as_uint(f);
  u32 r = u + 0x7fffu + ((u >> 16) & 1u);
  return (u16)(r >> 16);
}
__device__ __forceinline__ float sigm(float x){ return 1.0f / (1.0f + __expf(-x)); }
__device__ __forceinline__ float tanh_(float x){ return 2.0f / (1.0f + __expf(-2.0f * x)) - 1.0f; }
__device__ __forceinline__ float relu_(float x){ return x > 0.0f ? x : 0.0f; }

// LDS tile byte swizzle: row stride 256B, XOR row bits into byte bits 4-6 (T2)
__device__ __forceinline__ int swz(int r, int c){ return r * 256 + (c ^ ((r & 7) << 4)); }

__device__ __forceinline__ void zero8(float v[8]){
  #pragma unroll
  for (int j = 0; j < 8; j++) v[j] = 0.f;
}
__device__ __forceinline__ uint4 pack8(const float v[8]){
  uint4 o;
  o.x = f2bf(v[0]) | ((u32)f2bf(v[1]) << 16);
  o.y = f2bf(v[2]) | ((u32)f2bf(v[3]) << 16);
  o.z = f2bf(v[4]) | ((u32)f2bf(v[5]) << 16);
  o.w = f2bf(v[6]) | ((u32)f2bf(v[7]) << 16);
  return o;
}
__device__ __forceinline__ uint2 pack4(const f32x4& a){
  uint2 o;
  o.x = (u32)f2bf(a[0]) | ((u32)f2bf(a[1]) << 16);
  o.y = (u32)f2bf(a[2]) | ((u32)f2bf(a[3]) << 16);
  return o;
}

// ---------------- dtype sniffer (bf16 vs f32 inputs) ----------------
__global__ void k_sniff(const u32* __restrict__ g, int* __restrict__ flag){
  __shared__ int sh[2];
  if (threadIdx.x < 2) sh[threadIdx.x] = 0;
  __syncthreads();
  int c0 = 0, c1 = 0;
  for (int i = 0; i < 16; i++){
    u32 w = g[threadIdx.x * 16 + i];
    u32 lo = w & 0xFFFFu;
    if (lo == 0u) c0++;
    else { u32 e = (lo >> 7) & 0xFFu; if (e >= 96u && e <= 144u) c1++; }
  }
  atomicAdd(&sh[0], c0); atomicAdd(&sh[1], c1);
  __syncthreads();
  if (threadIdx.x == 0) *flag = (sh[0] < 512 && sh[1] > 2048) ? 1 : 0;
}

// all 13 weights -> f32 mirror arena (one launch)
__global__ void k_cvt_all(const void* p0, const void* p1, const void* p2, const void* p3,
                          const void* p4, const void* p5, const void* p6, const void* p7,
                          const void* p8, const void* p9, const void* p10, const void* p11,
                          const void* p12, float* __restrict__ wm, const int* __restrict__ flagp){
  int i = blockIdx.x * 256 + threadIdx.x;
  if (i >= 188416) return;
  const int offs[14] = {0,8192,16384,32768,40960,57344,73728,90112,106496,122880,139264,155648,172032,188416};
  const void* ps[13] = {p0,p1,p2,p3,p4,p5,p6,p7,p8,p9,p10,p11,p12};
  int w = 0;
  while (i >= offs[w + 1]) w++;
  int li = i - offs[w];
  wm[i] = (*flagp) ? bf2f(((const u16*)ps[w])[li]) : ((const float*)ps[w])[li];
}

// all MFMA B-fragment tables (one launch, 46 ks-blocks)
// frag arena block b (4096 u16) <- weight wi, local kstep ks:
//   frag[b][nt][lane][j] = W[ks*32 + (lane>>4)*8 + j][nt*16 + (lane&15)]
__global__ void k_mkfrag_all(const float* __restrict__ wm, u16* __restrict__ frag){
  const int wmo[13] = {0,8192,16384,32768,40960,57344,73728,90112,106496,122880,139264,155648,172032};
  const int nks[13] = {2,2,4,2,4,4,4,4,4,4,4,4,4};
  int b = blockIdx.x;            // 0..45
  int wi = 0, ks = b;
  while (ks >= nks[wi]){ ks -= nks[wi]; wi++; }
  const float* W = wm + wmo[wi];
  int nt = threadIdx.x >> 6, lane = threadIdx.x & 63;
  int kr = ks * 32 + ((lane >> 4) << 3);
  int col = nt * 16 + (lane & 15);
  u16* o = frag + (size_t)b * 4096 + nt * 512 + lane * 8;
  #pragma unroll
  for (int j = 0; j < 8; j++) o[j] = f2bf(W[(size_t)(kr + j) * 128 + col]);
}

// ---------------- dual-dtype row access ----------------
__device__ __forceinline__ const void* rowdt(const void* mat, size_t row, int W, int bf){
  return bf ? (const void*)((const u16*)mat + row * (size_t)W)
            : (const void*)((const float*)mat + row * (size_t)W);
}
__device__ __forceinline__ void load8(const void* rowbase, int c8, int bf, float v[8]){
  if (bf){
    uint4 d = ((const uint4*)rowbase)[c8];
    v[0]=bflo(d.x); v[1]=bfhi(d.x); v[2]=bflo(d.y); v[3]=bfhi(d.y);
    v[4]=bflo(d.z); v[5]=bfhi(d.z); v[6]=bflo(d.w); v[7]=bfhi(d.w);
  } else {
    const float4* p = (const float4*)rowbase + (c8 << 1);
    float4 a = p[0], b = p[1];
    v[0]=a.x; v[1]=a.y; v[2]=a.z; v[3]=a.w; v[4]=b.x; v[5]=b.y; v[6]=b.z; v[7]=b.w;
  }
}

// ---------------- unified CSR build ----------------
__global__ void k_hist_all(const int* __restrict__ Glgd, const int* __restrict__ Gd,
                           const int* __restrict__ Tlgd, const int* __restrict__ Td,
                           int* __restrict__ cnt){
  int e = blockIdx.x * 256 + threadIdx.x;
  if (e >= NE_ALL) return;
  int seg;
  if (e < ELG)                       seg = Glgd[e];
  else if (e < ELG + EG)             seg = SEG1 + Gd[e - ELG];
  else if (e < ELG + EG + ELGT)      seg = SEG2 + Tlgd[e - ELG - EG];
  else                               seg = SEG3 + Td[e - ELG - EG - ELGT];
  atomicAdd(&cnt[seg], 1);
}

__global__ void k_scan1(const int* __restrict__ cnt, int n, int* __restrict__ csum){
  int base = blockIdx.x * 4096, tid = threadIdx.x;
  int s = 0;
  for (int i = 0; i < 16; i++){ int idx = base + i * 256 + tid; if (idx < n) s += cnt[idx]; }
  __shared__ int red[4];
  for (int off = 32; off; off >>= 1) s += __shfl_down(s, off, 64);
  if ((tid & 63) == 0) red[tid >> 6] = s;
  __syncthreads();
  if (tid == 0) csum[blockIdx.x] = red[0] + red[1] + red[2] + red[3];
}

__global__ void k_scan2(int* csum, int nch, int* rowptr, int n){
  if (threadIdx.x == 0){
    int run = 0;
    for (int c = 0; c < nch; c++){ int t = csum[c]; csum[c] = run; run += t; }
    rowptr[n] = run;
  }
}

__global__ void k_scan3(const int* __restrict__ cnt, int n, const int* __restrict__ csum,
                        int* __restrict__ rowptr){
  __shared__ int buf[4096];
  __shared__ int tsum[256];
  int base = blockIdx.x * 4096, tid = threadIdx.x;
  for (int i = 0; i < 16; i++){ int idx = base + i * 256 + tid; buf[i * 256 + tid] = (idx < n) ? cnt[idx] : 0; }
  __syncthreads();
  int run = 0;
  for (int i = 0; i < 16; i++){ int v = buf[tid * 16 + i]; buf[tid * 16 + i] = run; run += v; }
  tsum[tid] = run;
  __syncthreads();
  for (int off = 1; off < 256; off <<= 1){
    int v = (tid >= off) ? tsum[tid - off] : 0;
    __syncthreads();
    tsum[tid] += v;
    __syncthreads();
  }
  int texcl = tsum[tid] - run;
  int cbase = csum[blockIdx.x];
  for (int i = 0; i < 16; i++){
    int idx = base + tid * 16 + i;
    if (idx < n) rowptr[idx] = cbase + texcl + buf[tid * 16 + i];
  }
}

__global__ void k_fill_all(const int* __restrict__ Glgd, const int* __restrict__ Glgs,
                           const int* __restrict__ Gd,
                           const int* __restrict__ Tlgd, const int* __restrict__ Tlgs,
                           const int* __restrict__ Td,
                           const int* __restrict__ rowptr, int* __restrict__ fill,
                           int* __restrict__ col){
  int e = blockIdx.x * 256 + threadIdx.x;
  if (e >= NE_ALL) return;
  int seg, srcv;
  if (e < ELG){                      seg = Glgd[e];                          srcv = Glgs[e]; }
  else if (e < ELG + EG){            int l = e - ELG;                        seg = SEG1 + Gd[l];  srcv = l; }
  else if (e < ELG + EG + ELGT){     int l = e - ELG - EG;                   seg = SEG2 + Tlgd[l]; srcv = Tlgs[l]; }
  else {                             int l = e - ELG - EG - ELGT;            seg = SEG3 + Td[l];  srcv = l; }
  int pos = atomicAdd(&fill[seg], 1);
  col[rowptr[seg] + pos] = srcv;
}

// ---------------- tile staging (256 threads, 64-row tiles, bf16 swizzled) ----------------

__device__ __forceinline__ void gather_tile(char* __restrict__ tile,
    const int* __restrict__ rowptr, const int* __restrict__ colidx,
    const u16* __restrict__ msg, int row0, int M)
{
  int tid = threadIdx.x;
  int rl = tid >> 2, q = tid & 3;
  int row = row0 + rl;
  float acc[4][8];
  #pragma unroll
  for (int v = 0; v < 4; v++) zero8(acc[v]);
  if (row < M){
    int p = rowptr[row], pe = rowptr[row + 1];
    for (; p < pe; ++p){
      int sr = colidx[p];
      const uint4* b = (const uint4*)(msg + (size_t)sr * 128);
      #pragma unroll
      for (int v = 0; v < 4; v++){
        uint4 d = b[v * 4 + q];
        acc[v][0] += bflo(d.x); acc[v][1] += bfhi(d.x);
        acc[v][2] += bflo(d.y); acc[v][3] += bfhi(d.y);
        acc[v][4] += bflo(d.z); acc[v][5] += bfhi(d.z);
        acc[v][6] += bflo(d.w); acc[v][7] += bfhi(d.w);
      }
    }
  }
  #pragma unroll
  for (int v = 0; v < 4; v++)
    *(uint4*)(tile + swz(rl, (v * 4 + q) * 16)) = pack8(acc[v]);
}

__device__ __forceinline__ void stage_cat_tile(char* __restrict__ tile,
    const void* __restrict__ Gf, const void* __restrict__ Gef,
    const int* __restrict__ Gsrc, int row0, int M, int bf)
{
  int tid = threadIdx.x, rl = tid >> 2, q = tid & 3;
  int row = row0 + rl;
  float A0[8], A1[8], B0[8], B1[8];
  if (row < M){
    int sr = Gsrc[row];
    const void* ra = rowdt(Gf, (size_t)sr, 64, bf);
    const void* rb = rowdt(Gef, (size_t)row, 64, bf);
    load8(ra, q, bf, A0); load8(ra, q + 4, bf, A1);
    load8(rb, q, bf, B0); load8(rb, q + 4, bf, B1);
  } else { zero8(A0); zero8(A1); zero8(B0); zero8(B1); }
  *(uint4*)(tile + swz(rl, q * 16))             = pack8(A0);
  *(uint4*)(tile + swz(rl, (q + 4) * 16))       = pack8(A1);
  *(uint4*)(tile + swz(rl, 128 + q * 16))       = pack8(B0);
  *(uint4*)(tile + swz(rl, 128 + (q + 4) * 16)) = pack8(B1);
}

__device__ __forceinline__ void stage_w64_tile(char* __restrict__ tile,
    const void* __restrict__ mat, int row0, int M, int bf)
{
  int tid = threadIdx.x, rl = tid >> 2, q = tid & 3;
  int row = row0 + rl;
  float A0[8], A1[8];
  if (row < M){
    const void* ra = rowdt(mat, (size_t)row, 64, bf);
    load8(ra, q, bf, A0); load8(ra, q + 4, bf, A1);
  } else { zero8(A0); zero8(A1); }
  *(uint4*)(tile + swz(rl, q * 16))       = pack8(A0);
  *(uint4*)(tile + swz(rl, (q + 4) * 16)) = pack8(A1);
}

// emb[Tid[idx ? idx[row] : row]] -> tile (dual-dtype emb)
__device__ __forceinline__ void stage_emb_tile(char* __restrict__ tile,
    const void* __restrict__ emb, const int* __restrict__ Tid,
    const int* __restrict__ idx, int row0, int M, int bf)
{
  int tid = threadIdx.x, rl = tid >> 2, q = tid & 3;
  int row = row0 + rl;
  if (row < M){
    int n = idx ? idx[row] : row;
    int id = Tid[n];
    const void* rb = rowdt(emb, (size_t)id, 128, bf);
    #pragma unroll
    for (int v = 0; v < 4; v++){
      float t[8]; load8(rb, v * 4 + q, bf, t);
      *(uint4*)(tile + swz(rl, (v * 4 + q) * 16)) = pack8(t);
    }
  } else {
    uint4 z = make_uint4(0, 0, 0, 0);
    #pragma unroll
    for (int v = 0; v < 4; v++)
      *(uint4*)(tile + swz(rl, (v * 4 + q) * 16)) = z;
  }
}

// acc[nt] += A_tile(stripe rows, K=32*ksteps) @ Wfrag
__device__ __forceinline__ void mma_acc(const char* __restrict__ tile, int stripe,
    const u16* __restrict__ frag, int ksteps, f32x4 (&acc)[8])
{
  int lane = threadIdx.x & 63;
  int ar = stripe + (lane & 15);
  int acb = (lane >> 4) << 4;
  for (int ks = 0; ks < ksteps; ks++){
    bf16x8 a = *(const bf16x8*)(tile + swz(ar, ks * 64 + acb));
    const u16* fb = frag + (size_t)ks * 4096 + lane * 8;
    #pragma unroll
    for (int nt = 0; nt < 8; nt++){
      bf16x8 b = *(const bf16x8*)(fb + (size_t)nt * 512);
      acc[nt] = __builtin_amdgcn_mfma_f32_16x16x32_bf16(a, b, acc[nt], 0, 0, 0);
    }
  }
}

#define INIT_ACC(A) { _Pragma("unroll") for (int n_=0;n_<8;n_++){ A[n_][0]=0.f; A[n_][1]=0.f; A[n_][2]=0.f; A[n_][3]=0.f; } }

__device__ __forceinline__ void repack_store(const char* __restrict__ tile,
    u16* __restrict__ dst, int row0, int M)
{
  int rl = threadIdx.x >> 2, q = threadIdx.x & 3;
  int grow = row0 + rl;
  if (grow < M){
    #pragma unroll
    for (int v = 0; v < 4; v++){
      uint4 d = *(const uint4*)(tile + swz(rl, (v * 4 + q) * 16));
      *(uint4*)(dst + (size_t)grow * 128 + (size_t)(v * 4 + q) * 8) = d;
    }
  }
}

// frag-major uint2 slot for xz/xr/xh: [blk][w][nt][lane][r0..r3]
__device__ __forceinline__ size_t fslot(int blk, int w, int nt){
  return ((((size_t)blk * 4 + w) * 8 + nt) * 64 + (threadIdx.x & 63)) * 4;
}

// ---------------- merged pipeline kernels ----------------

// blocks [0,GEG): msgG = relu(Gf[Gsrc]@W1 + Gef@W2)
// blocks [GEG,GEG+GET): xz/xr/xh = emb[Tid[Tsrc]]@{Wz,Wr,Wh}; msgT = sig(xz)*tanh(xh)
__global__ __launch_bounds__(256) void k_init(
    const void* __restrict__ Gf, const void* __restrict__ Gef, const int* __restrict__ Gsrc,
    const u16* __restrict__ fWcat, const int* __restrict__ flagp, u16* __restrict__ msgG,
    const void* __restrict__ emb, const int* __restrict__ Tid, const int* __restrict__ Tsrc,
    const u16* __restrict__ fWz, const u16* __restrict__ fWr, const u16* __restrict__ fWh,
    u16* __restrict__ xzf, u16* __restrict__ xrf, u16* __restrict__ xhf, u16* __restrict__ msgT)
{
  __shared__ char t0[TILE_BYTES];
  int bf = *flagp;
  int w = threadIdx.x >> 6, lane = threadIdx.x & 63, stripe = w * 16;
  if (blockIdx.x < GEG){
    int row0 = blockIdx.x * 64;
    stage_cat_tile(t0, Gf, Gef, Gsrc, row0, EG, bf);
    __syncthreads();
    f32x4 acc[8]; INIT_ACC(acc);
    mma_acc(t0, stripe, fWcat, 4, acc);
    #pragma unroll
    for (int nt = 0; nt < 8; nt++)
      #pragma unroll
      for (int r = 0; r < 4; r++){
        int rt = stripe + ((lane >> 4) << 2) + r;
        int cb = nt * 32 + (lane & 15) * 2;
        *(u16*)(t0 + swz(rt, cb)) = f2bf(relu_(acc[nt][r]));
      }
    __syncthreads();
    repack_store(t0, msgG, row0, EG);
  } else {
    int blk = blockIdx.x - GEG;
    int row0 = blk * 64;
    stage_emb_tile(t0, emb, Tid, Tsrc, row0, ET, bf);
    __syncthreads();
    f32x4 aZ[8]; INIT_ACC(aZ);
    mma_acc(t0, stripe, fWz, 4, aZ);
    {
      f32x4 aR[8]; INIT_ACC(aR);
      mma_acc(t0, stripe, fWr, 4, aR);
      #pragma unroll
      for (int nt = 0; nt < 8; nt++)
        *(uint2*)(xrf + fslot(blk, w, nt)) = pack4(aR[nt]);
    }
    f32x4 aH[8]; INIT_ACC(aH);
    mma_acc(t0, stripe, fWh, 4, aH);
    #pragma unroll
    for (int nt = 0; nt < 8; nt++){
      *(uint2*)(xzf + fslot(blk, w, nt)) = pack4(aZ[nt]);
      *(uint2*)(xhf + fslot(blk, w, nt)) = pack4(aH[nt]);
      #pragma unroll
      for (int r = 0; r < 4; r++){
        int rt = stripe + ((lane >> 4) << 2) + r;
        int cb = nt * 32 + (lane & 15) * 2;
        *(u16*)(t0 + swz(rt, cb)) = f2bf(sigm(aZ[nt][r]) * tanh_(aH[nt][r]));
      }
    }
    __syncthreads();
    repack_store(t0, msgT, row0, ET);
  }
}

// blocks [0,GEG): G iter; blocks [GEG,GEG+GET): T GRU iter
__global__ __launch_bounds__(256) void k_iter(
    const u16* __restrict__ msgInG, u16* __restrict__ msgOutG,
    const void* __restrict__ Gf, const void* __restrict__ Gef, const int* __restrict__ Gsrc,
    const int* __restrict__ rp, const int* __restrict__ col,
    const u16* __restrict__ fWcat, const u16* __restrict__ fW3, const int* __restrict__ flagp,
    const u16* __restrict__ msgInT, u16* __restrict__ msgOutT,
    const u16* __restrict__ fUz, const u16* __restrict__ fUr, const u16* __restrict__ fUh,
    const u16* __restrict__ xzf, const u16* __restrict__ xrf, const u16* __restrict__ xhf)
{
  __shared__ char t0[TILE_BYTES];
  __shared__ char t1[TILE_BYTES];
  int w = threadIdx.x >> 6, lane = threadIdx.x & 63, stripe = w * 16;
  if (blockIdx.x < GEG){
    int bf = *flagp;
    int row0 = blockIdx.x * 64;
    stage_cat_tile(t0, Gf, Gef, Gsrc, row0, EG, bf);
    gather_tile(t1, rp, col, msgInG, row0, EG);
    __syncthreads();
    f32x4 acc[8]; INIT_ACC(acc);
    mma_acc(t0, stripe, fWcat, 4, acc);
    mma_acc(t1, stripe, fW3, 4, acc);
    #pragma unroll
    for (int nt = 0; nt < 8; nt++)
      #pragma unroll
      for (int r = 0; r < 4; r++){
        int rt = stripe + ((lane >> 4) << 2) + r;
        int cb = nt * 32 + (lane & 15) * 2;
        *(u16*)(t1 + swz(rt, cb)) = f2bf(relu_(acc[nt][r]));
      }
    __syncthreads();
    repack_store(t1, msgOutG, row0, EG);
  } else {
    int blk = blockIdx.x - GEG;
    int row0 = blk * 64;
    gather_tile(t0, rp + SEG2, col, msgInT, row0, ET);
    __syncthreads();
    f32x4 aZ[8], aR[8];
    INIT_ACC(aZ); INIT_ACC(aR);
    mma_acc(t0, stripe, fUz, 4, aZ);
    mma_acc(t0, stripe, fUr, 4, aR);
    float zz[8][4];
    #pragma unroll
    for (int nt = 0; nt < 8; nt++){
      uint2 z4 = *(const uint2*)(xzf + fslot(blk, w, nt));
      uint2 r4 = *(const uint2*)(xrf + fslot(blk, w, nt));
      float xzv[4] = {bflo(z4.x), bfhi(z4.x), bflo(z4.y), bfhi(z4.y)};
      float xrv[4] = {bflo(r4.x), bfhi(r4.x), bflo(r4.y), bfhi(r4.y)};
      #pragma unroll
      for (int r = 0; r < 4; r++){
        int rt = stripe + ((lane >> 4) << 2) + r;
        int cb = nt * 32 + (lane & 15) * 2;
        float s = bf2f(*(const u16*)(t0 + swz(rt, cb)));
        float z = sigm(xzv[r] + aZ[nt][r]);
        float rr = sigm(xrv[r] + aR[nt][r]);
        zz[nt][r] = z;
        *(u16*)(t1 + swz(rt, cb)) = f2bf(rr * s);
      }
    }
    __syncthreads();
    f32x4 aH[8]; INIT_ACC(aH);
    mma_acc(t1, stripe, fUh, 4, aH);
    #pragma unroll
    for (int nt = 0; nt < 8; nt++){
      uint2 h4 = *(const uint2*)(xhf + fslot(blk, w, nt));
      float xhv[4] = {bflo(h4.x), bfhi(h4.x), bflo(h4.y), bfhi(h4.y)};
      #pragma unroll
      for (int r = 0; r < 4; r++){
        int rt = stripe + ((lane >> 4) << 2) + r;
        int cb = nt * 32 + (lane & 15) * 2;
        float s = bf2f(*(const u16*)(t0 + swz(rt, cb)));
        float h = tanh_(xhv[r] + aH[nt][r]);
        float m = (1.f - zz[nt][r]) * s + zz[nt][r] * h;
        *(u16*)(t0 + swz(rt, cb)) = f2bf(m);
      }
    }
    __syncthreads();
    repack_store(t0, msgOutT, row0, ET);
  }
}

// blocks [0,GNG): out_G = relu(Gf@U1G + segsum(msgG)@U2G)
// blocks [GNG,GNG+GNT): out_T = relu(emb[Tid]@U1T + segsum(msgT)@U2T)
__global__ __launch_bounds__(256) void k_readout(
    const void* __restrict__ Gf, const u16* __restrict__ msgG,
    const int* __restrict__ rp, const int* __restrict__ col,
    const u16* __restrict__ fU1G, const u16* __restrict__ fU2G,
    const void* __restrict__ emb, const int* __restrict__ Tid, const u16* __restrict__ msgT,
    const u16* __restrict__ fU1T, const u16* __restrict__ fU2T,
    const int* __restrict__ flagp, float* __restrict__ out)
{
  __shared__ char t0[TILE_BYTES];
  __shared__ char t1[TILE_BYTES];
  int bf = *flagp;
  int w = threadIdx.x >> 6, lane = threadIdx.x & 63, stripe = w * 16;
  if (blockIdx.x < GNG){
    int row0 = blockIdx.x * 64;
    stage_w64_tile(t0, Gf, row0, NG, bf);
    gather_tile(t1, rp + SEG1, col, msgG, row0, NG);
    __syncthreads();
    f32x4 acc[8]; INIT_ACC(acc);
    mma_acc(t0, stripe, fU1G, 2, acc);
    mma_acc(t1, stripe, fU2G, 4, acc);
    #pragma unroll
    for (int nt = 0; nt < 8; nt++)
      #pragma unroll
      for (int r = 0; r < 4; r++){
        int R = row0 + stripe + ((lane >> 4) << 2) + r;
        if (R < NG) out[(size_t)R * 128 + nt * 16 + (lane & 15)] = relu_(acc[nt][r]);
      }
  } else {
    int row0 = (blockIdx.x - GNG) * 64;
    stage_emb_tile(t0, emb, Tid, nullptr, row0, NT, bf);
    gather_tile(t1, rp + SEG3, col, msgT, row0, NT);
    __syncthreads();
    f32x4 acc[8]; INIT_ACC(acc);
    mma_acc(t0, stripe, fU1T, 4, acc);
    mma_acc(t1, stripe, fU2T, 4, acc);
    #pragma unroll
    for (int nt = 0; nt < 8; nt++)
      #pragma unroll
      for (int r = 0; r < 4; r++){
        int R = row0 + stripe + ((lane >> 4) << 2) + r;
        if (R < NT) out[(size_t)(NG + R) * 128 + nt * 16 + (lane & 15)] = relu_(acc[nt][r]);
      }
  }
}

// ---------------- host launcher ----------------
extern "C" void kernel_launch(void* const* d_in, const int* in_sizes, int n_in,
                              void* d_out, int out_size, void* d_ws, size_t ws_size,
                              hipStream_t stream)
{
  const void* G_f      = d_in[0];
  const void* G_ef     = d_in[1];
  const int*  G_src    = (const int*)d_in[2];
  const int*  G_dst    = (const int*)d_in[3];
  const int*  G_lg_src = (const int*)d_in[4];
  const int*  G_lg_dst = (const int*)d_in[5];
  const int*  T_id     = (const int*)d_in[6];
  const int*  T_src    = (const int*)d_in[7];
  const int*  T_dst    = (const int*)d_in[8];
  const int*  T_lg_src = (const int*)d_in[9];
  const int*  T_lg_dst = (const int*)d_in[10];
  const void* emb      = d_in[11];
  float* out = (float*)d_out;
  (void)in_sizes; (void)n_in; (void)out_size; (void)ws_size;

  size_t off = 0;
  auto alloc = [&](size_t bytes) -> char* {
    char* p = (char*)d_ws + off;
    off += (bytes + 255) & ~(size_t)255;
    return p;
  };

  int*   flag = (int*)alloc(256);
  float* wm   = (float*)alloc(sizeof(float) * 188416);
  u16*   frag = (u16*)alloc(2 * 46 * 4096);
  const u16* fWcat = frag;
  const u16* fW3   = frag + (size_t)4  * 4096;
  const u16* fU1G  = frag + (size_t)8  * 4096;
  const u16* fU2G  = frag + (size_t)10 * 4096;
  const u16* fWz   = frag + (size_t)14 * 4096;
  const u16* fUz   = frag + (size_t)18 * 4096;
  const u16* fWr   = frag + (size_t)22 * 4096;
  const u16* fUr   = frag + (size_t)26 * 4096;
  const u16* fWh   = frag + (size_t)30 * 4096;
  const u16* fUh   = frag + (size_t)34 * 4096;
  const u16* fU1T  = frag + (size_t)38 * 4096;
  const u16* fU2T  = frag + (size_t)42 * 4096;

  int* rp   = (int*)alloc(sizeof(int) * (NSEG_ALL + 1));
  int* col  = (int*)alloc(sizeof(int) * NE_ALL);
  int* cnt  = (int*)alloc(sizeof(int) * 2 * NSEG_ALL);   // hist + fill counters
  int* csum = (int*)alloc(sizeof(int) * 256);
  u16* msgGA = (u16*)alloc((size_t)EG * 128 * 2);
  u16* msgGB = (u16*)alloc((size_t)EG * 128 * 2);
  u16* xzf   = (u16*)alloc((size_t)GET * 8192 * 2);
  u16* xrf   = (u16*)alloc((size_t)GET * 8192 * 2);
  u16* xhf   = (u16*)alloc((size_t)GET * 8192 * 2);
  u16* msgTA = (u16*)alloc((size_t)ET * 128 * 2);
  u16* msgTB = (u16*)alloc((size_t)ET * 128 * 2);

  // setup: dtype flag -> weight mirrors -> fragment tables (3 launches)
  k_sniff<<<1, 256, 0, stream>>>((const u32*)G_ef, flag);
  k_cvt_all<<<(188416 + 255) / 256, 256, 0, stream>>>(
      d_in[12], d_in[13], d_in[14], d_in[15], d_in[16], d_in[17], d_in[18],
      d_in[19], d_in[20], d_in[21], d_in[22], d_in[23], d_in[24], wm, flag);
  k_mkfrag_all<<<46, 512, 0, stream>>>(wm, frag);

  // unified CSR build (1 memset + 5 kernels)
  hipMemsetAsync(cnt, 0, sizeof(int) * 2 * NSEG_ALL, stream);
  k_hist_all<<<(NE_ALL + 255) / 256, 256, 0, stream>>>(G_lg_dst, G_dst, T_lg_dst, T_dst, cnt);
  int nch = (NSEG_ALL + 4095) / 4096;
  k_scan1<<<nch, 256, 0, stream>>>(cnt, NSEG_ALL, csum);
  k_scan2<<<1, 64, 0, stream>>>(csum, nch, rp, NSEG_ALL);
  k_scan3<<<nch, 256, 0, stream>>>(cnt, NSEG_ALL, csum, rp);
  k_fill_all<<<(NE_ALL + 255) / 256, 256, 0, stream>>>(
      G_lg_dst, G_lg_src, G_dst, T_lg_dst, T_lg_src, T_dst, rp, cnt + NSEG_ALL, col);

  // merged pipeline: init, 3 iters, readout (5 launches)
  k_init<<<GEG + GET, 256, 0, stream>>>(G_f, G_ef, G_src, fWcat, flag, msgGA,
                                        emb, T_id, T_src, fWz, fWr, fWh, xzf, xrf, xhf, msgTA);
  k_iter<<<GEG + GET, 256, 0, stream>>>(msgGA, msgGB, G_f, G_ef, G_src, rp, col, fWcat, fW3, flag,
                                        msgTA, msgTB, fUz, fUr, fUh, xzf, xrf, xhf);
  k_iter<<<GEG + GET, 256, 0, stream>>>(msgGB, msgGA, G_f, G_ef, G_src, rp, col, fWcat, fW3, flag,
                                        msgTB, msgTA, fUz, fUr, fUh, xzf, xrf, xhf);
  k_iter<<<GEG + GET, 256, 0, stream>>>(msgGA, msgGB, G_f, G_ef, G_src, rp, col, fWcat, fW3, flag,
                                        msgTA, msgTB, fUz, fUr, fUh, xzf, xrf, xhf);
  k_readout<<<GNG + GNT, 256, 0, stream>>>(G_f, msgGB, rp, col, fU1G, fU2G,
                                           emb, T_id, msgTB, fU1T, fU2T, flag, out);
}

// Round 6
// 1246.033 us; speedup vs baseline: 2.2094x; 1.0839x over previous
//
#include <hip/hip_runtime.h>

#define NG 100000
#define EG 400000
#define ELG 1200000
#define NT 50000
#define ET 100000
#define ELGT 300000

#define GEG ((EG + 63) / 64)     // 6250
#define GET ((ET + 63) / 64)     // 1563
#define GNG ((NG + 63) / 64)     // 1563
#define GNT ((NT + 63) / 64)     // 782

// concatenated CSR segment space: [G_lg(EG) | G_dst(NG) | T_lg(ET) | T_dst(NT)]
#define SEG1 EG
#define SEG2 (EG + NG)
#define SEG3 (EG + NG + ET)
#define NSEG_ALL (EG + NG + ET + NT)
#define NE_ALL (ELG + EG + ELGT + ET)

typedef unsigned short u16;
typedef unsigned int u32;
typedef __attribute__((ext_vector_type(8))) short bf16x8;
typedef __attribute__((ext_vector_type(4))) float f32x4;

#define TILE_B 16384   // one 64-row x 128-col bf16 tile (row stride 256 B)

__device__ __forceinline__ float bflo(u32 p){ return __uint_as_float(p << 16); }
__device__ __forceinline__ float bfhi(u32 p){ return __uint_as_float(p & 0xffff0000u); }
__device__ __forceinline__ float bf2f(u16 h){ return __uint_as_float(((u32)h) << 16); }
__device__ __forceinline__ u16 f2bf(float f){
  u32 u = __float_as_uint(f);
  u32 r = u + 0x7fffu + ((u >> 16) & 1u);
  return (u16)(r >> 16);
}
__device__ __forceinline__ float sigm(float x){ return 1.0f / (1.0f + __expf(-x)); }
__device__ __forceinline__ float tanh_(float x){ return 2.0f / (1.0f + __expf(-2.0f * x)) - 1.0f; }
__device__ __forceinline__ float relu_(float x){ return x > 0.0f ? x : 0.0f; }
__device__ __forceinline__ void wfence(){ __builtin_amdgcn_wave_barrier(); }

// LDS tile byte swizzle (T2): row stride 256B, XOR row bits into byte bits 4-6
__device__ __forceinline__ int swz(int r, int c){ return r * 256 + (c ^ ((r & 7) << 4)); }

__device__ __forceinline__ void zero8(float v[8]){
  #pragma unroll
  for (int j = 0; j < 8; j++) v[j] = 0.f;
}
__device__ __forceinline__ uint4 pack8(const float v[8]){
  uint4 o;
  o.x = f2bf(v[0]) | ((u32)f2bf(v[1]) << 16);
  o.y = f2bf(v[2]) | ((u32)f2bf(v[3]) << 16);
  o.z = f2bf(v[4]) | ((u32)f2bf(v[5]) << 16);
  o.w = f2bf(v[6]) | ((u32)f2bf(v[7]) << 16);
  return o;
}
__device__ __forceinline__ uint2 pack4(const f32x4& a){
  uint2 o;
  o.x = (u32)f2bf(a[0]) | ((u32)f2bf(a[1]) << 16);
  o.y = (u32)f2bf(a[2]) | ((u32)f2bf(a[3]) << 16);
  return o;
}
__device__ __forceinline__ uint2 pack4a(const float v[4]){
  uint2 o;
  o.x = (u32)f2bf(v[0]) | ((u32)f2bf(v[1]) << 16);
  o.y = (u32)f2bf(v[2]) | ((u32)f2bf(v[3]) << 16);
  return o;
}
__device__ __forceinline__ void unp4(uint2 u, float v[4]){
  v[0] = bflo(u.x); v[1] = bfhi(u.x); v[2] = bflo(u.y); v[3] = bfhi(u.y);
}
__device__ __forceinline__ bf16x8 packfrag(const float v[8]){
  union { uint4 u; bf16x8 b; } c; c.u = pack8(v); return c.b;
}
__device__ __forceinline__ bf16x8 zfrag(){
  union { uint4 u; bf16x8 b; } c; c.u = make_uint4(0, 0, 0, 0); return c.b;
}
__device__ __forceinline__ bf16x8 as_frag(uint4 u){
  union { uint4 u; bf16x8 b; } c; c.u = u; return c.b;
}

// ---------------- dtype sniffer (bf16 vs f32 inputs) ----------------
__global__ void k_sniff(const u32* __restrict__ g, int* __restrict__ flag){
  __shared__ int sh[2];
  if (threadIdx.x < 2) sh[threadIdx.x] = 0;
  __syncthreads();
  int c0 = 0, c1 = 0;
  for (int i = 0; i < 16; i++){
    u32 w = g[threadIdx.x * 16 + i];
    u32 lo = w & 0xFFFFu;
    if (lo == 0u) c0++;
    else { u32 e = (lo >> 7) & 0xFFu; if (e >= 96u && e <= 144u) c1++; }
  }
  atomicAdd(&sh[0], c0); atomicAdd(&sh[1], c1);
  __syncthreads();
  if (threadIdx.x == 0) *flag = (sh[0] < 512 && sh[1] > 2048) ? 1 : 0;
}

// all 13 weights -> f32 mirror arena (one launch)
__global__ void k_cvt_all(const void* p0, const void* p1, const void* p2, const void* p3,
                          const void* p4, const void* p5, const void* p6, const void* p7,
                          const void* p8, const void* p9, const void* p10, const void* p11,
                          const void* p12, float* __restrict__ wm, const int* __restrict__ flagp){
  int i = blockIdx.x * 256 + threadIdx.x;
  if (i >= 188416) return;
  const int offs[14] = {0,8192,16384,32768,40960,57344,73728,90112,106496,122880,139264,155648,172032,188416};
  const void* ps[13] = {p0,p1,p2,p3,p4,p5,p6,p7,p8,p9,p10,p11,p12};
  int w = 0;
  while (i >= offs[w + 1]) w++;
  int li = i - offs[w];
  wm[i] = (*flagp) ? bf2f(((const u16*)ps[w])[li]) : ((const float*)ps[w])[li];
}

// all MFMA B-fragment tables (one launch, 46 ks-blocks)
__global__ void k_mkfrag_all(const float* __restrict__ wm, u16* __restrict__ frag){
  const int wmo[13] = {0,8192,16384,32768,40960,57344,73728,90112,106496,122880,139264,155648,172032};
  const int nks[13] = {2,2,4,2,4,4,4,4,4,4,4,4,4};
  int b = blockIdx.x;            // 0..45
  int wi = 0, ks = b;
  while (ks >= nks[wi]){ ks -= nks[wi]; wi++; }
  const float* W = wm + wmo[wi];
  int nt = threadIdx.x >> 6, lane = threadIdx.x & 63;
  int kr = ks * 32 + ((lane >> 4) << 3);
  int col = nt * 16 + (lane & 15);
  u16* o = frag + (size_t)b * 4096 + nt * 512 + lane * 8;
  #pragma unroll
  for (int j = 0; j < 8; j++) o[j] = f2bf(W[(size_t)(kr + j) * 128 + col]);
}

// ---------------- dual-dtype row access ----------------
__device__ __forceinline__ const void* rowdt(const void* mat, size_t row, int W, int bf){
  return bf ? (const void*)((const u16*)mat + row * (size_t)W)
            : (const void*)((const float*)mat + row * (size_t)W);
}
__device__ __forceinline__ void load8(const void* rowbase, int c8, int bf, float v[8]){
  if (bf){
    uint4 d = ((const uint4*)rowbase)[c8];
    v[0]=bflo(d.x); v[1]=bfhi(d.x); v[2]=bflo(d.y); v[3]=bfhi(d.y);
    v[4]=bflo(d.z); v[5]=bfhi(d.z); v[6]=bflo(d.w); v[7]=bfhi(d.w);
  } else {
    const float4* p = (const float4*)rowbase + (c8 << 1);
    float4 a = p[0], b = p[1];
    v[0]=a.x; v[1]=a.y; v[2]=a.z; v[3]=a.w; v[4]=b.x; v[5]=b.y; v[6]=b.z; v[7]=b.w;
  }
}

// ---------------- unified CSR build ----------------
__global__ void k_hist_all(const int* __restrict__ Glgd, const int* __restrict__ Gd,
                           const int* __restrict__ Tlgd, const int* __restrict__ Td,
                           int* __restrict__ cnt){
  int e = blockIdx.x * 256 + threadIdx.x;
  if (e >= NE_ALL) return;
  int seg;
  if (e < ELG)                       seg = Glgd[e];
  else if (e < ELG + EG)             seg = SEG1 + Gd[e - ELG];
  else if (e < ELG + EG + ELGT)      seg = SEG2 + Tlgd[e - ELG - EG];
  else                               seg = SEG3 + Td[e - ELG - EG - ELGT];
  atomicAdd(&cnt[seg], 1);
}

__global__ void k_scan1(const int* __restrict__ cnt, int n, int* __restrict__ csum){
  int base = blockIdx.x * 4096, tid = threadIdx.x;
  int s = 0;
  for (int i = 0; i < 16; i++){ int idx = base + i * 256 + tid; if (idx < n) s += cnt[idx]; }
  __shared__ int red[4];
  for (int off = 32; off; off >>= 1) s += __shfl_down(s, off, 64);
  if ((tid & 63) == 0) red[tid >> 6] = s;
  __syncthreads();
  if (tid == 0) csum[blockIdx.x] = red[0] + red[1] + red[2] + red[3];
}

__global__ void k_scan2(int* csum, int nch, int* rowptr, int n){
  if (threadIdx.x == 0){
    int run = 0;
    for (int c = 0; c < nch; c++){ int t = csum[c]; csum[c] = run; run += t; }
    rowptr[n] = run;
  }
}

__global__ void k_scan3(const int* __restrict__ cnt, int n, const int* __restrict__ csum,
                        int* __restrict__ rowptr){
  __shared__ int buf[4096];
  __shared__ int tsum[256];
  int base = blockIdx.x * 4096, tid = threadIdx.x;
  for (int i = 0; i < 16; i++){ int idx = base + i * 256 + tid; buf[i * 256 + tid] = (idx < n) ? cnt[idx] : 0; }
  __syncthreads();
  int run = 0;
  for (int i = 0; i < 16; i++){ int v = buf[tid * 16 + i]; buf[tid * 16 + i] = run; run += v; }
  tsum[tid] = run;
  __syncthreads();
  for (int off = 1; off < 256; off <<= 1){
    int v = (tid >= off) ? tsum[tid - off] : 0;
    __syncthreads();
    tsum[tid] += v;
    __syncthreads();
  }
  int texcl = tsum[tid] - run;
  int cbase = csum[blockIdx.x];
  for (int i = 0; i < 16; i++){
    int idx = base + tid * 16 + i;
    if (idx < n) rowptr[idx] = cbase + texcl + buf[tid * 16 + i];
  }
}

__global__ void k_fill_all(const int* __restrict__ Glgd, const int* __restrict__ Glgs,
                           const int* __restrict__ Gd,
                           const int* __restrict__ Tlgd, const int* __restrict__ Tlgs,
                           const int* __restrict__ Td,
                           const int* __restrict__ rowptr, int* __restrict__ fill,
                           int* __restrict__ col){
  int e = blockIdx.x * 256 + threadIdx.x;
  if (e >= NE_ALL) return;
  int seg, srcv;
  if (e < ELG){                      seg = Glgd[e];                           srcv = Glgs[e]; }
  else if (e < ELG + EG){            int l = e - ELG;                         seg = SEG1 + Gd[l];   srcv = l; }
  else if (e < ELG + EG + ELGT){     int l = e - ELG - EG;                    seg = SEG2 + Tlgd[l]; srcv = Tlgs[l]; }
  else {                             int l = e - ELG - EG - ELGT;             seg = SEG3 + Td[l];   srcv = l; }
  int pos = atomicAdd(&fill[seg], 1);
  col[rowptr[seg] + pos] = srcv;
}

// ---------------- register-direct gather + MFMA ----------------

__device__ __forceinline__ void acc8_add(float (&a)[8], uint4 d){
  a[0] += bflo(d.x); a[1] += bfhi(d.x);
  a[2] += bflo(d.y); a[3] += bfhi(d.y);
  a[4] += bflo(d.z); a[5] += bfhi(d.z);
  a[6] += bflo(d.w); a[7] += bfhi(d.w);
}

// CSR gather-sum of bf16 msg rows directly into A-fragment accumulators.
// Lane owns its A-row; chunk kg (lane>>4): elements [ks*32+kg*8, +8) per kstep.
__device__ __forceinline__ void gather_accum(const int* __restrict__ rowptr,
    const int* __restrict__ colidx, const u16* __restrict__ msg,
    int row, int M, int kg, float (&acc)[4][8])
{
  #pragma unroll
  for (int ks = 0; ks < 4; ks++) zero8(acc[ks]);
  if (row >= M) return;
  int p = rowptr[row], pe = rowptr[row + 1];
  for (; p + 1 < pe; p += 2){
    const uint4* b0 = (const uint4*)(msg + (size_t)colidx[p] * 128);
    const uint4* b1 = (const uint4*)(msg + (size_t)colidx[p + 1] * 128);
    uint4 v0[4], v1[4];
    #pragma unroll
    for (int ks = 0; ks < 4; ks++){ v0[ks] = b0[ks * 4 + kg]; v1[ks] = b1[ks * 4 + kg]; }
    #pragma unroll
    for (int ks = 0; ks < 4; ks++){ acc8_add(acc[ks], v0[ks]); acc8_add(acc[ks], v1[ks]); }
  }
  if (p < pe){
    const uint4* b0 = (const uint4*)(msg + (size_t)colidx[p] * 128);
    #pragma unroll
    for (int ks = 0; ks < 4; ks++){ uint4 v = b0[ks * 4 + kg]; acc8_add(acc[ks], v); }
  }
}

// acc[nt] += A(frags in regs) @ Wfrag, KS ksteps
template<int KS>
__device__ __forceinline__ void mma_f(const bf16x8* a, const u16* __restrict__ frag,
                                      f32x4 (&acc)[8])
{
  int lane = threadIdx.x & 63;
  #pragma unroll
  for (int ks = 0; ks < KS; ks++){
    const u16* fb = frag + (size_t)ks * 4096 + lane * 8;
    #pragma unroll
    for (int nt = 0; nt < 8; nt++){
      bf16x8 b = *(const bf16x8*)(fb + (size_t)nt * 512);
      acc[nt] = __builtin_amdgcn_mfma_f32_16x16x32_bf16(a[ks], b, acc[nt], 0, 0, 0);
    }
  }
}

#define INIT_ACC(A) { _Pragma("unroll") for (int n_=0;n_<8;n_++){ A[n_][0]=0.f; A[n_][1]=0.f; A[n_][2]=0.f; A[n_][3]=0.f; } }

// tile (bf16, swizzled, wave-stripe-local) -> row-major global bf16
__device__ __forceinline__ void repack_store(const char* __restrict__ tile,
    u16* __restrict__ dst, int row0, int M)
{
  int rl = threadIdx.x >> 2, q = threadIdx.x & 3;
  int grow = row0 + rl;
  if (grow < M){
    #pragma unroll
    for (int v = 0; v < 4; v++){
      uint4 d = *(const uint4*)(tile + swz(rl, (v * 4 + q) * 16));
      *(uint4*)(dst + (size_t)grow * 128 + (size_t)(v * 4 + q) * 8) = d;
    }
  }
}

// frag-major uint2 slot: [blk][w][nt][lane][4 bf16]
__device__ __forceinline__ size_t fslot(int blk, int w, int nt){
  return ((((size_t)blk * 4 + w) * 8 + nt) * 64 + (threadIdx.x & 63)) * 4;
}

// load the 4 A-fragments of concat(Gf[Gsrc[arow]], Gef[arow]) for this lane
__device__ __forceinline__ void load_catfrag(const void* __restrict__ Gf,
    const void* __restrict__ Gef, const int* __restrict__ Gsrc,
    int arow, int kg, int bf, bf16x8 (&fC)[4])
{
  if (arow < EG){
    int sr = Gsrc[arow];
    const void* ra = rowdt(Gf, (size_t)sr, 64, bf);
    const void* rb = rowdt(Gef, (size_t)arow, 64, bf);
    float t[8];
    load8(ra, kg, bf, t);     fC[0] = packfrag(t);
    load8(ra, 4 + kg, bf, t); fC[1] = packfrag(t);
    load8(rb, kg, bf, t);     fC[2] = packfrag(t);
    load8(rb, 4 + kg, bf, t); fC[3] = packfrag(t);
  } else {
    #pragma unroll
    for (int ks = 0; ks < 4; ks++) fC[ks] = zfrag();
  }
}

// ---------------- merged pipeline kernels (wave-local, no block barriers) ----------------

// blocks [0,GET): xz/xr/xh = emb[Tid[Tsrc]]@{Wz,Wr,Wh}; msgT = sig(xz)*tanh(xh)
// blocks [GET,GET+GEG): msgG = relu(Gf[Gsrc]@W1 + Gef@W2)
__global__ __launch_bounds__(256) void k_init(
    const void* __restrict__ Gf, const void* __restrict__ Gef, const int* __restrict__ Gsrc,
    const u16* __restrict__ fWcat, const int* __restrict__ flagp, u16* __restrict__ msgG,
    const void* __restrict__ emb, const int* __restrict__ Tid, const int* __restrict__ Tsrc,
    const u16* __restrict__ fWz, const u16* __restrict__ fWr, const u16* __restrict__ fWh,
    u16* __restrict__ xzf, u16* __restrict__ xrf, u16* __restrict__ xhf, u16* __restrict__ msgT)
{
  __shared__ char t0[TILE_B];
  int bf = *flagp;
  int lane = threadIdx.x & 63, w = threadIdx.x >> 6;
  int stripe = w * 16, kg = lane >> 4, m16 = lane & 15;
  if (blockIdx.x < GET){
    int blk = blockIdx.x, row0 = blk * 64, arow = row0 + stripe + m16;
    bf16x8 fE[4];
    if (arow < ET){
      int id = Tid[Tsrc[arow]];
      const void* rb = rowdt(emb, (size_t)id, 128, bf);
      #pragma unroll
      for (int ks = 0; ks < 4; ks++){
        float t[8]; load8(rb, ks * 4 + kg, bf, t); fE[ks] = packfrag(t);
      }
    } else {
      #pragma unroll
      for (int ks = 0; ks < 4; ks++) fE[ks] = zfrag();
    }
    f32x4 aZ[8], aR[8]; INIT_ACC(aZ); INIT_ACC(aR);
    mma_f<4>(fE, fWz, aZ);
    mma_f<4>(fE, fWr, aR);
    #pragma unroll
    for (int nt = 0; nt < 8; nt++){
      *(uint2*)(xzf + fslot(blk, w, nt)) = pack4(aZ[nt]);
      *(uint2*)(xrf + fslot(blk, w, nt)) = pack4(aR[nt]);
    }
    f32x4 aH[8]; INIT_ACC(aH);
    mma_f<4>(fE, fWh, aH);
    #pragma unroll
    for (int nt = 0; nt < 8; nt++){
      *(uint2*)(xhf + fslot(blk, w, nt)) = pack4(aH[nt]);
      #pragma unroll
      for (int r = 0; r < 4; r++){
        int rt = stripe + (kg << 2) + r;
        int cb = nt * 32 + m16 * 2;
        *(u16*)(t0 + swz(rt, cb)) = f2bf(sigm(aZ[nt][r]) * tanh_(aH[nt][r]));
      }
    }
    wfence();
    repack_store(t0, msgT, row0, ET);
  } else {
    int blk = blockIdx.x - GET, row0 = blk * 64, arow = row0 + stripe + m16;
    bf16x8 fC[4];
    load_catfrag(Gf, Gef, Gsrc, arow, kg, bf, fC);
    f32x4 acc[8]; INIT_ACC(acc);
    mma_f<4>(fC, fWcat, acc);
    #pragma unroll
    for (int nt = 0; nt < 8; nt++)
      #pragma unroll
      for (int r = 0; r < 4; r++){
        int rt = stripe + (kg << 2) + r;
        int cb = nt * 32 + m16 * 2;
        *(u16*)(t0 + swz(rt, cb)) = f2bf(relu_(acc[nt][r]));
      }
    wfence();
    repack_store(t0, msgG, row0, EG);
  }
}

// blocks [0,GET): T GRU iter; blocks [GET,GET+GEG): G iter (base recomputed in regs)
__global__ __launch_bounds__(256) void k_iter(
    const u16* __restrict__ msgInG, u16* __restrict__ msgOutG,
    const void* __restrict__ Gf, const void* __restrict__ Gef, const int* __restrict__ Gsrc,
    const int* __restrict__ rp, const int* __restrict__ col,
    const u16* __restrict__ fWcat, const u16* __restrict__ fW3, const int* __restrict__ flagp,
    const u16* __restrict__ msgInT, u16* __restrict__ msgOutT,
    const u16* __restrict__ fUz, const u16* __restrict__ fUr, const u16* __restrict__ fUh,
    const u16* __restrict__ xzf, const u16* __restrict__ xrf, const u16* __restrict__ xhf)
{
  __shared__ char t0[TILE_B];
  int lane = threadIdx.x & 63, w = threadIdx.x >> 6;
  int stripe = w * 16, kg = lane >> 4, m16 = lane & 15;
  if (blockIdx.x < GET){
    // ---- T GRU step ----
    int blk = blockIdx.x, row0 = blk * 64, arow = row0 + stripe + m16;
    float ga[4][8];
    gather_accum(rp + SEG2, col, msgInT, arow, ET, kg, ga);
    bf16x8 fS[4];
    #pragma unroll
    for (int ks = 0; ks < 4; ks++){
      uint4 pk = pack8(ga[ks]);
      *(uint4*)(t0 + swz(stripe + m16, ks * 64 + kg * 16)) = pk;  // S tile (A-layout)
      fS[ks] = as_frag(pk);
    }
    f32x4 aZ[8], aR[8]; INIT_ACC(aZ); INIT_ACC(aR);
    mma_f<4>(fS, fUz, aZ);
    mma_f<4>(fS, fUr, aR);
    wfence();
    uint2 zpk[8], wpk[8];
    #pragma unroll
    for (int nt = 0; nt < 8; nt++){
      uint2 z4 = *(const uint2*)(xzf + fslot(blk, w, nt));
      uint2 r4 = *(const uint2*)(xrf + fslot(blk, w, nt));
      float xzv[4], xrv[4], zv[4], wv[4];
      unp4(z4, xzv); unp4(r4, xrv);
      #pragma unroll
      for (int r = 0; r < 4; r++){
        int rt = stripe + (kg << 2) + r;
        int cb = nt * 32 + m16 * 2;
        float s = bf2f(*(const u16*)(t0 + swz(rt, cb)));   // read S at C-position
        float z = sigm(xzv[r] + aZ[nt][r]);
        float rr = sigm(xrv[r] + aR[nt][r]);
        zv[r] = z;
        wv[r] = s * (1.f - z);
        *(u16*)(t0 + swz(rt, cb)) = f2bf(rr * s);          // tile becomes r*s
      }
      zpk[nt] = pack4a(zv); wpk[nt] = pack4a(wv);
    }
    wfence();
    bf16x8 fRS[4];
    #pragma unroll
    for (int ks = 0; ks < 4; ks++)
      fRS[ks] = *(const bf16x8*)(t0 + swz(stripe + m16, ks * 64 + kg * 16));
    f32x4 aH[8]; INIT_ACC(aH);
    mma_f<4>(fRS, fUh, aH);
    wfence();
    #pragma unroll
    for (int nt = 0; nt < 8; nt++){
      uint2 h4 = *(const uint2*)(xhf + fslot(blk, w, nt));
      float xhv[4], zv[4], wv[4];
      unp4(h4, xhv); unp4(zpk[nt], zv); unp4(wpk[nt], wv);
      #pragma unroll
      for (int r = 0; r < 4; r++){
        float h = tanh_(xhv[r] + aH[nt][r]);
        float m = wv[r] + zv[r] * h;      // (1-z)s + zh
        int rt = stripe + (kg << 2) + r;
        int cb = nt * 32 + m16 * 2;
        *(u16*)(t0 + swz(rt, cb)) = f2bf(m);
      }
    }
    wfence();
    repack_store(t0, msgOutT, row0, ET);
  } else {
    // ---- G iter: msgOut = relu(Gf[Gsrc]@W1 + Gef@W2 + segsum(msgIn)@W3) ----
    int bf = *flagp;
    int blk = blockIdx.x - GET, row0 = blk * 64, arow = row0 + stripe + m16;
    bf16x8 fC[4];
    load_catfrag(Gf, Gef, Gsrc, arow, kg, bf, fC);
    float ga[4][8];
    gather_accum(rp, col, msgInG, arow, EG, kg, ga);
    bf16x8 fS[4];
    #pragma unroll
    for (int ks = 0; ks < 4; ks++) fS[ks] = packfrag(ga[ks]);
    f32x4 acc[8]; INIT_ACC(acc);
    mma_f<4>(fS, fW3, acc);
    mma_f<4>(fC, fWcat, acc);
    #pragma unroll
    for (int nt = 0; nt < 8; nt++)
      #pragma unroll
      for (int r = 0; r < 4; r++){
        int rt = stripe + (kg << 2) + r;
        int cb = nt * 32 + m16 * 2;
        *(u16*)(t0 + swz(rt, cb)) = f2bf(relu_(acc[nt][r]));
      }
    wfence();
    repack_store(t0, msgOutG, row0, EG);
  }
}

// blocks [0,GNT): out_T = relu(emb[Tid]@U1T + segsum(msgT)@U2T)
// blocks [GNT,GNT+GNG): out_G = relu(Gf@U1G + segsum(msgG)@U2G)
__global__ __launch_bounds__(256) void k_readout(
    const void* __restrict__ Gf, const u16* __restrict__ msgG,
    const int* __restrict__ rp, const int* __restrict__ col,
    const u16* __restrict__ fU1G, const u16* __restrict__ fU2G,
    const void* __restrict__ emb, const int* __restrict__ Tid, const u16* __restrict__ msgT,
    const u16* __restrict__ fU1T, const u16* __restrict__ fU2T,
    const int* __restrict__ flagp, float* __restrict__ out)
{
  int bf = *flagp;
  int lane = threadIdx.x & 63, w = threadIdx.x >> 6;
  int stripe = w * 16, kg = lane >> 4, m16 = lane & 15;
  if (blockIdx.x < GNT){
    int row0 = blockIdx.x * 64, arow = row0 + stripe + m16;
    bf16x8 fE[4];
    if (arow < NT){
      int id = Tid[arow];
      const void* rb = rowdt(emb, (size_t)id, 128, bf);
      #pragma unroll
      for (int ks = 0; ks < 4; ks++){
        float t[8]; load8(rb, ks * 4 + kg, bf, t); fE[ks] = packfrag(t);
      }
    } else {
      #pragma unroll
      for (int ks = 0; ks < 4; ks++) fE[ks] = zfrag();
    }
    float ga[4][8];
    gather_accum(rp + SEG3, col, msgT, arow, NT, kg, ga);
    bf16x8 fS[4];
    #pragma unroll
    for (int ks = 0; ks < 4; ks++) fS[ks] = packfrag(ga[ks]);
    f32x4 acc[8]; INIT_ACC(acc);
    mma_f<4>(fE, fU1T, acc);
    mma_f<4>(fS, fU2T, acc);
    #pragma unroll
    for (int nt = 0; nt < 8; nt++)
      #pragma unroll
      for (int r = 0; r < 4; r++){
        int R = row0 + stripe + (kg << 2) + r;
        if (R < NT) out[(size_t)(NG + R) * 128 + nt * 16 + m16] = relu_(acc[nt][r]);
      }
  } else {
    int row0 = (blockIdx.x - GNT) * 64, arow = row0 + stripe + m16;
    bf16x8 fG[2];
    if (arow < NG){
      const void* ra = rowdt(Gf, (size_t)arow, 64, bf);
      float t[8];
      load8(ra, kg, bf, t);     fG[0] = packfrag(t);
      load8(ra, 4 + kg, bf, t); fG[1] = packfrag(t);
    } else { fG[0] = zfrag(); fG[1] = zfrag(); }
    float ga[4][8];
    gather_accum(rp + SEG1, col, msgG, arow, NG, kg, ga);
    bf16x8 fS[4];
    #pragma unroll
    for (int ks = 0; ks < 4; ks++) fS[ks] = packfrag(ga[ks]);
    f32x4 acc[8]; INIT_ACC(acc);
    mma_f<2>(fG, fU1G, acc);
    mma_f<4>(fS, fU2G, acc);
    #pragma unroll
    for (int nt = 0; nt < 8; nt++)
      #pragma unroll
      for (int r = 0; r < 4; r++){
        int R = row0 + stripe + (kg << 2) + r;
        if (R < NG) out[(size_t)R * 128 + nt * 16 + m16] = relu_(acc[nt][r]);
      }
  }
}

// ---------------- host launcher ----------------
extern "C" void kernel_launch(void* const* d_in, const int* in_sizes, int n_in,
                              void* d_out, int out_size, void* d_ws, size_t ws_size,
                              hipStream_t stream)
{
  const void* G_f      = d_in[0];
  const void* G_ef     = d_in[1];
  const int*  G_src    = (const int*)d_in[2];
  const int*  G_dst    = (const int*)d_in[3];
  const int*  G_lg_src = (const int*)d_in[4];
  const int*  G_lg_dst = (const int*)d_in[5];
  const int*  T_id     = (const int*)d_in[6];
  const int*  T_src    = (const int*)d_in[7];
  const int*  T_dst    = (const int*)d_in[8];
  const int*  T_lg_src = (const int*)d_in[9];
  const int*  T_lg_dst = (const int*)d_in[10];
  const void* emb      = d_in[11];
  float* out = (float*)d_out;
  (void)in_sizes; (void)n_in; (void)out_size; (void)ws_size;

  size_t off = 0;
  auto alloc = [&](size_t bytes) -> char* {
    char* p = (char*)d_ws + off;
    off += (bytes + 255) & ~(size_t)255;
    return p;
  };

  int*   flag = (int*)alloc(256);
  float* wm   = (float*)alloc(sizeof(float) * 188416);
  u16*   frag = (u16*)alloc(2 * 46 * 4096);
  const u16* fWcat = frag;
  const u16* fW3   = frag + (size_t)4  * 4096;
  const u16* fU1G  = frag + (size_t)8  * 4096;
  const u16* fU2G  = frag + (size_t)10 * 4096;
  const u16* fWz   = frag + (size_t)14 * 4096;
  const u16* fUz   = frag + (size_t)18 * 4096;
  const u16* fWr   = frag + (size_t)22 * 4096;
  const u16* fUr   = frag + (size_t)26 * 4096;
  const u16* fWh   = frag + (size_t)30 * 4096;
  const u16* fUh   = frag + (size_t)34 * 4096;
  const u16* fU1T  = frag + (size_t)38 * 4096;
  const u16* fU2T  = frag + (size_t)42 * 4096;

  int* rp   = (int*)alloc(sizeof(int) * (NSEG_ALL + 1));
  int* col  = (int*)alloc(sizeof(int) * NE_ALL);
  int* cnt  = (int*)alloc(sizeof(int) * 2 * NSEG_ALL);
  int* csum = (int*)alloc(sizeof(int) * 256);
  u16* msgGA = (u16*)alloc((size_t)EG * 128 * 2);
  u16* msgGB = (u16*)alloc((size_t)EG * 128 * 2);
  u16* xzf   = (u16*)alloc((size_t)GET * 8192 * 2);
  u16* xrf   = (u16*)alloc((size_t)GET * 8192 * 2);
  u16* xhf   = (u16*)alloc((size_t)GET * 8192 * 2);
  u16* msgTA = (u16*)alloc((size_t)ET * 128 * 2);
  u16* msgTB = (u16*)alloc((size_t)ET * 128 * 2);
  // total ws ≈ 350 MB (same as round-4 footprint that passed)

  // setup: dtype flag -> weight mirrors -> fragment tables (3 launches)
  k_sniff<<<1, 256, 0, stream>>>((const u32*)G_ef, flag);
  k_cvt_all<<<(188416 + 255) / 256, 256, 0, stream>>>(
      d_in[12], d_in[13], d_in[14], d_in[15], d_in[16], d_in[17], d_in[18],
      d_in[19], d_in[20], d_in[21], d_in[22], d_in[23], d_in[24], wm, flag);
  k_mkfrag_all<<<46, 512, 0, stream>>>(wm, frag);

  // unified CSR build (1 memset + 5 kernels)
  hipMemsetAsync(cnt, 0, sizeof(int) * 2 * NSEG_ALL, stream);
  k_hist_all<<<(NE_ALL + 255) / 256, 256, 0, stream>>>(G_lg_dst, G_dst, T_lg_dst, T_dst, cnt);
  int nch = (NSEG_ALL + 4095) / 4096;
  k_scan1<<<nch, 256, 0, stream>>>(cnt, NSEG_ALL, csum);
  k_scan2<<<1, 64, 0, stream>>>(csum, nch, rp, NSEG_ALL);
  k_scan3<<<nch, 256, 0, stream>>>(cnt, NSEG_ALL, csum, rp);
  k_fill_all<<<(NE_ALL + 255) / 256, 256, 0, stream>>>(
      G_lg_dst, G_lg_src, G_dst, T_lg_dst, T_lg_src, T_dst, rp, cnt + NSEG_ALL, col);

  // merged pipeline (5 launches, T blocks first)
  k_init<<<GET + GEG, 256, 0, stream>>>(G_f, G_ef, G_src, fWcat, flag, msgGA,
                                        emb, T_id, T_src, fWz, fWr, fWh, xzf, xrf, xhf, msgTA);
  k_iter<<<GET + GEG, 256, 0, stream>>>(msgGA, msgGB, G_f, G_ef, G_src, rp, col, fWcat, fW3, flag,
                                        msgTA, msgTB, fUz, fUr, fUh, xzf, xrf, xhf);
  k_iter<<<GET + GEG, 256, 0, stream>>>(msgGB, msgGA, G_f, G_ef, G_src, rp, col, fWcat, fW3, flag,
                                        msgTB, msgTA, fUz, fUr, fUh, xzf, xrf, xhf);
  k_iter<<<GET + GEG, 256, 0, stream>>>(msgGA, msgGB, G_f, G_ef, G_src, rp, col, fWcat, fW3, flag,
                                        msgTA, msgTB, fUz, fUr, fUh, xzf, xrf, xhf);
  k_readout<<<GNT + GNG, 256, 0, stream>>>(G_f, msgGB, rp, col, fU1G, fU2G,
                                           emb, T_id, msgTB, fU1T, fU2T, flag, out);
}

// Round 7
// 1097.791 us; speedup vs baseline: 2.5077x; 1.1350x over previous
//
#include <hip/hip_runtime.h>

#define NG 100000
#define EG 400000
#define ELG 1200000
#define NT 50000
#define ET 100000
#define ELGT 300000

#define GEG ((EG + 63) / 64)     // 6250
#define GET ((ET + 63) / 64)     // 1563
#define GNG ((NG + 63) / 64)     // 1563
#define GNT ((NT + 63) / 64)     // 782

// concatenated CSR segment space: [G_lg(EG) | G_dst(NG) | T_lg(ET) | T_dst(NT)]
#define SEG1 EG
#define SEG2 (EG + NG)
#define SEG3 (EG + NG + ET)
#define NSEG_ALL (EG + NG + ET + NT)
#define NE_ALL (ELG + EG + ELGT + ET)
// padded CSR upper bound: every segment rounded up to multiple of 4
#define NE_PAD (NE_ALL + 3 * NSEG_ALL + 64)

typedef unsigned short u16;
typedef unsigned int u32;
typedef __attribute__((ext_vector_type(8))) short bf16x8;
typedef __attribute__((ext_vector_type(4))) float f32x4;

#define TILE_B 16384   // one 64-row x 128-col bf16 tile (row stride 256 B)

__device__ __forceinline__ float bflo(u32 p){ return __uint_as_float(p << 16); }
__device__ __forceinline__ float bfhi(u32 p){ return __uint_as_float(p & 0xffff0000u); }
__device__ __forceinline__ float bf2f(u16 h){ return __uint_as_float(((u32)h) << 16); }
__device__ __forceinline__ u16 f2bf(float f){
  u32 u = __float_as_uint(f);
  u32 r = u + 0x7fffu + ((u >> 16) & 1u);
  return (u16)(r >> 16);
}
__device__ __forceinline__ float sigm(float x){ return 1.0f / (1.0f + __expf(-x)); }
__device__ __forceinline__ float tanh_(float x){ return 2.0f / (1.0f + __expf(-2.0f * x)) - 1.0f; }
__device__ __forceinline__ float relu_(float x){ return x > 0.0f ? x : 0.0f; }
__device__ __forceinline__ void wfence(){ __builtin_amdgcn_wave_barrier(); }

// LDS tile byte swizzle (T2): row stride 256B, XOR row bits into byte bits 4-6
__device__ __forceinline__ int swz(int r, int c){ return r * 256 + (c ^ ((r & 7) << 4)); }

__device__ __forceinline__ void zero8(float v[8]){
  #pragma unroll
  for (int j = 0; j < 8; j++) v[j] = 0.f;
}
__device__ __forceinline__ uint4 pack8(const float v[8]){
  uint4 o;
  o.x = f2bf(v[0]) | ((u32)f2bf(v[1]) << 16);
  o.y = f2bf(v[2]) | ((u32)f2bf(v[3]) << 16);
  o.z = f2bf(v[4]) | ((u32)f2bf(v[5]) << 16);
  o.w = f2bf(v[6]) | ((u32)f2bf(v[7]) << 16);
  return o;
}
__device__ __forceinline__ uint2 pack4(const f32x4& a){
  uint2 o;
  o.x = (u32)f2bf(a[0]) | ((u32)f2bf(a[1]) << 16);
  o.y = (u32)f2bf(a[2]) | ((u32)f2bf(a[3]) << 16);
  return o;
}
__device__ __forceinline__ void unp4(uint2 u, float v[4]){
  v[0] = bflo(u.x); v[1] = bfhi(u.x); v[2] = bflo(u.y); v[3] = bfhi(u.y);
}
__device__ __forceinline__ bf16x8 packfrag(const float v[8]){
  union { uint4 u; bf16x8 b; } c; c.u = pack8(v); return c.b;
}
__device__ __forceinline__ bf16x8 zfrag(){
  union { uint4 u; bf16x8 b; } c; c.u = make_uint4(0, 0, 0, 0); return c.b;
}
__device__ __forceinline__ bf16x8 as_frag(uint4 u){
  union { uint4 u; bf16x8 b; } c; c.u = u; return c.b;
}

// ---------------- dtype sniffer (bf16 vs f32 inputs) ----------------
__global__ void k_sniff(const u32* __restrict__ g, int* __restrict__ flag){
  __shared__ int sh[2];
  if (threadIdx.x < 2) sh[threadIdx.x] = 0;
  __syncthreads();
  int c0 = 0, c1 = 0;
  for (int i = 0; i < 16; i++){
    u32 w = g[threadIdx.x * 16 + i];
    u32 lo = w & 0xFFFFu;
    if (lo == 0u) c0++;
    else { u32 e = (lo >> 7) & 0xFFu; if (e >= 96u && e <= 144u) c1++; }
  }
  atomicAdd(&sh[0], c0); atomicAdd(&sh[1], c1);
  __syncthreads();
  if (threadIdx.x == 0) *flag = (sh[0] < 512 && sh[1] > 2048) ? 1 : 0;
}

// all 13 weights -> f32 mirror arena (one launch)
__global__ void k_cvt_all(const void* p0, const void* p1, const void* p2, const void* p3,
                          const void* p4, const void* p5, const void* p6, const void* p7,
                          const void* p8, const void* p9, const void* p10, const void* p11,
                          const void* p12, float* __restrict__ wm, const int* __restrict__ flagp){
  int i = blockIdx.x * 256 + threadIdx.x;
  if (i >= 188416) return;
  const int offs[14] = {0,8192,16384,32768,40960,57344,73728,90112,106496,122880,139264,155648,172032,188416};
  const void* ps[13] = {p0,p1,p2,p3,p4,p5,p6,p7,p8,p9,p10,p11,p12};
  int w = 0;
  while (i >= offs[w + 1]) w++;
  int li = i - offs[w];
  wm[i] = (*flagp) ? bf2f(((const u16*)ps[w])[li]) : ((const float*)ps[w])[li];
}

// all MFMA B-fragment tables (one launch, 46 ks-blocks)
__global__ void k_mkfrag_all(const float* __restrict__ wm, u16* __restrict__ frag){
  const int wmo[13] = {0,8192,16384,32768,40960,57344,73728,90112,106496,122880,139264,155648,172032};
  const int nks[13] = {2,2,4,2,4,4,4,4,4,4,4,4,4};
  int b = blockIdx.x;            // 0..45
  int wi = 0, ks = b;
  while (ks >= nks[wi]){ ks -= nks[wi]; wi++; }
  const float* W = wm + wmo[wi];
  int nt = threadIdx.x >> 6, lane = threadIdx.x & 63;
  int kr = ks * 32 + ((lane >> 4) << 3);
  int col = nt * 16 + (lane & 15);
  u16* o = frag + (size_t)b * 4096 + nt * 512 + lane * 8;
  #pragma unroll
  for (int j = 0; j < 8; j++) o[j] = f2bf(W[(size_t)(kr + j) * 128 + col]);
}

// ---------------- dual-dtype row access ----------------
__device__ __forceinline__ const void* rowdt(const void* mat, size_t row, int W, int bf){
  return bf ? (const void*)((const u16*)mat + row * (size_t)W)
            : (const void*)((const float*)mat + row * (size_t)W);
}
__device__ __forceinline__ void load8(const void* rowbase, int c8, int bf, float v[8]){
  if (bf){
    uint4 d = ((const uint4*)rowbase)[c8];
    v[0]=bflo(d.x); v[1]=bfhi(d.x); v[2]=bflo(d.y); v[3]=bfhi(d.y);
    v[4]=bflo(d.z); v[5]=bfhi(d.z); v[6]=bflo(d.w); v[7]=bfhi(d.w);
  } else {
    const float4* p = (const float4*)rowbase + (c8 << 1);
    float4 a = p[0], b = p[1];
    v[0]=a.x; v[1]=a.y; v[2]=a.z; v[3]=a.w; v[4]=b.x; v[5]=b.y; v[6]=b.z; v[7]=b.w;
  }
}

// ---------------- unified CSR build (padded to multiples of 4) ----------------
__global__ void k_hist_all(const int* __restrict__ Glgd, const int* __restrict__ Gd,
                           const int* __restrict__ Tlgd, const int* __restrict__ Td,
                           int* __restrict__ cnt){
  int e = blockIdx.x * 256 + threadIdx.x;
  if (e >= NE_ALL) return;
  int seg;
  if (e < ELG)                       seg = Glgd[e];
  else if (e < ELG + EG)             seg = SEG1 + Gd[e - ELG];
  else if (e < ELG + EG + ELGT)      seg = SEG2 + Tlgd[e - ELG - EG];
  else                               seg = SEG3 + Td[e - ELG - EG - ELGT];
  atomicAdd(&cnt[seg], 1);
}

__global__ void k_scan1(const int* __restrict__ cnt, int n, int* __restrict__ csum){
  int base = blockIdx.x * 4096, tid = threadIdx.x;
  int s = 0;
  for (int i = 0; i < 16; i++){
    int idx = base + i * 256 + tid;
    if (idx < n) s += (cnt[idx] + 3) & ~3;      // padded count
  }
  __shared__ int red[4];
  for (int off = 32; off; off >>= 1) s += __shfl_down(s, off, 64);
  if ((tid & 63) == 0) red[tid >> 6] = s;
  __syncthreads();
  if (tid == 0) csum[blockIdx.x] = red[0] + red[1] + red[2] + red[3];
}

__global__ void k_scan2(int* csum, int nch, int* rowptr, int n){
  if (threadIdx.x == 0){
    int run = 0;
    for (int c = 0; c < nch; c++){ int t = csum[c]; csum[c] = run; run += t; }
    rowptr[n] = run;
  }
}

__global__ void k_scan3(const int* __restrict__ cnt, int n, const int* __restrict__ csum,
                        int* __restrict__ rowptr){
  __shared__ int buf[4096];
  __shared__ int tsum[256];
  int base = blockIdx.x * 4096, tid = threadIdx.x;
  for (int i = 0; i < 16; i++){
    int idx = base + i * 256 + tid;
    buf[i * 256 + tid] = (idx < n) ? ((cnt[idx] + 3) & ~3) : 0;   // padded count
  }
  __syncthreads();
  int run = 0;
  for (int i = 0; i < 16; i++){ int v = buf[tid * 16 + i]; buf[tid * 16 + i] = run; run += v; }
  tsum[tid] = run;
  __syncthreads();
  for (int off = 1; off < 256; off <<= 1){
    int v = (tid >= off) ? tsum[tid - off] : 0;
    __syncthreads();
    tsum[tid] += v;
    __syncthreads();
  }
  int texcl = tsum[tid] - run;
  int cbase = csum[blockIdx.x];
  for (int i = 0; i < 16; i++){
    int idx = base + tid * 16 + i;
    if (idx < n) rowptr[idx] = cbase + texcl + buf[tid * 16 + i];
  }
}

__global__ void k_fill_all(const int* __restrict__ Glgd, const int* __restrict__ Glgs,
                           const int* __restrict__ Gd,
                           const int* __restrict__ Tlgd, const int* __restrict__ Tlgs,
                           const int* __restrict__ Td,
                           const int* __restrict__ rowptr, int* __restrict__ fill,
                           int* __restrict__ col){
  int e = blockIdx.x * 256 + threadIdx.x;
  if (e >= NE_ALL) return;
  int seg, srcv;
  if (e < ELG){                      seg = Glgd[e];                           srcv = Glgs[e]; }
  else if (e < ELG + EG){            int l = e - ELG;                         seg = SEG1 + Gd[l];   srcv = l; }
  else if (e < ELG + EG + ELGT){     int l = e - ELG - EG;                    seg = SEG2 + Tlgd[l]; srcv = Tlgs[l]; }
  else {                             int l = e - ELG - EG - ELGT;             seg = SEG3 + Td[l];   srcv = l; }
  int pos = atomicAdd(&fill[seg], 1);
  col[rowptr[seg] + pos] = srcv;
}

// fill the padding tail of every segment with the dummy (zero) row index
__global__ void k_fill_pad(const int* __restrict__ cnt, const int* __restrict__ rowptr,
                           int* __restrict__ col){
  int seg = blockIdx.x * 256 + threadIdx.x;
  if (seg >= NSEG_ALL) return;
  int dummy = (seg < SEG2) ? EG : ET;          // msgG dummy row / msgT dummy row
  int start = rowptr[seg] + cnt[seg];
  int end = rowptr[seg + 1];
  for (int q = start; q < end; q++) col[q] = dummy;
}

// zero the dummy msg rows (ws is poisoned 0xAA)
__global__ void k_zero_dummy(u16* a, u16* b, u16* c, u16* d){
  int i = threadIdx.x;
  if (i < 128){
    a[(size_t)EG * 128 + i] = 0; b[(size_t)EG * 128 + i] = 0;
    c[(size_t)ET * 128 + i] = 0; d[(size_t)ET * 128 + i] = 0;
  }
}

// ---------------- register-direct gather + MFMA ----------------

__device__ __forceinline__ void acc8_add(float (&a)[8], uint4 d){
  a[0] += bflo(d.x); a[1] += bfhi(d.x);
  a[2] += bflo(d.y); a[3] += bfhi(d.y);
  a[4] += bflo(d.z); a[5] += bfhi(d.z);
  a[6] += bflo(d.w); a[7] += bfhi(d.w);
}

// CSR gather-sum (rows padded to x4) of bf16 msg rows into A-fragment accumulators.
// Lane owns its A-row; chunk kg (lane>>4): elements [ks*32+kg*8, +8) per kstep.
// Each batch fires 16 independent loads before accumulating.
__device__ __forceinline__ void gather_accum(const int* __restrict__ rowptr,
    const int* __restrict__ colidx, const u16* __restrict__ msg,
    int row, int M, int kg, float (&acc)[4][8])
{
  #pragma unroll
  for (int ks = 0; ks < 4; ks++) zero8(acc[ks]);
  if (row >= M) return;
  int p = rowptr[row], pe = rowptr[row + 1];
  for (; p < pe; p += 4){
    int i0 = colidx[p], i1 = colidx[p + 1], i2 = colidx[p + 2], i3 = colidx[p + 3];
    const uint4* b0 = (const uint4*)(msg + (size_t)i0 * 128);
    const uint4* b1 = (const uint4*)(msg + (size_t)i1 * 128);
    const uint4* b2 = (const uint4*)(msg + (size_t)i2 * 128);
    const uint4* b3 = (const uint4*)(msg + (size_t)i3 * 128);
    uint4 v0[4], v1[4], v2[4], v3[4];
    #pragma unroll
    for (int ks = 0; ks < 4; ks++){
      v0[ks] = b0[ks * 4 + kg]; v1[ks] = b1[ks * 4 + kg];
      v2[ks] = b2[ks * 4 + kg]; v3[ks] = b3[ks * 4 + kg];
    }
    #pragma unroll
    for (int ks = 0; ks < 4; ks++){
      acc8_add(acc[ks], v0[ks]); acc8_add(acc[ks], v1[ks]);
      acc8_add(acc[ks], v2[ks]); acc8_add(acc[ks], v3[ks]);
    }
  }
}

// acc[nt] += A(frags in regs) @ Wfrag, KS ksteps
template<int KS>
__device__ __forceinline__ void mma_f(const bf16x8* a, const u16* __restrict__ frag,
                                      f32x4 (&acc)[8])
{
  int lane = threadIdx.x & 63;
  #pragma unroll
  for (int ks = 0; ks < KS; ks++){
    const u16* fb = frag + (size_t)ks * 4096 + lane * 8;
    #pragma unroll
    for (int nt = 0; nt < 8; nt++){
      bf16x8 b = *(const bf16x8*)(fb + (size_t)nt * 512);
      acc[nt] = __builtin_amdgcn_mfma_f32_16x16x32_bf16(a[ks], b, acc[nt], 0, 0, 0);
    }
  }
}

#define INIT_ACC(A) { _Pragma("unroll") for (int n_=0;n_<8;n_++){ A[n_][0]=0.f; A[n_][1]=0.f; A[n_][2]=0.f; A[n_][3]=0.f; } }

// tile (bf16, swizzled, wave-stripe-local) -> row-major global bf16
__device__ __forceinline__ void repack_store(const char* __restrict__ tile,
    u16* __restrict__ dst, int row0, int M)
{
  int rl = threadIdx.x >> 2, q = threadIdx.x & 3;
  int grow = row0 + rl;
  if (grow < M){
    #pragma unroll
    for (int v = 0; v < 4; v++){
      uint4 d = *(const uint4*)(tile + swz(rl, (v * 4 + q) * 16));
      *(uint4*)(dst + (size_t)grow * 128 + (size_t)(v * 4 + q) * 8) = d;
    }
  }
}

// frag-major uint2 slot: [blk][w][nt][lane][4 bf16]
__device__ __forceinline__ size_t fslot(int blk, int w, int nt){
  return ((((size_t)blk * 4 + w) * 8 + nt) * 64 + (threadIdx.x & 63)) * 4;
}

// load the 4 A-fragments of concat(Gf[Gsrc[arow]], Gef[arow]) for this lane
__device__ __forceinline__ void load_catfrag(const void* __restrict__ Gf,
    const void* __restrict__ Gef, const int* __restrict__ Gsrc,
    int arow, int kg, int bf, bf16x8 (&fC)[4])
{
  if (arow < EG){
    int sr = Gsrc[arow];
    const void* ra = rowdt(Gf, (size_t)sr, 64, bf);
    const void* rb = rowdt(Gef, (size_t)arow, 64, bf);
    float t[8];
    load8(ra, kg, bf, t);     fC[0] = packfrag(t);
    load8(ra, 4 + kg, bf, t); fC[1] = packfrag(t);
    load8(rb, kg, bf, t);     fC[2] = packfrag(t);
    load8(rb, 4 + kg, bf, t); fC[3] = packfrag(t);
  } else {
    #pragma unroll
    for (int ks = 0; ks < 4; ks++) fC[ks] = zfrag();
  }
}

// ---------------- merged pipeline kernels (wave-local, single MFMA accumulator) ----------------

// blocks [0,GET): xz/xr/xh = emb[Tid[Tsrc]]@{Wz,Wr,Wh}; msgT = sig(xz)*tanh(xh)
// blocks [GET,GET+GEG): msgG = relu(Gf[Gsrc]@W1 + Gef@W2)
__global__ __launch_bounds__(256, 4) void k_init(
    const void* __restrict__ Gf, const void* __restrict__ Gef, const int* __restrict__ Gsrc,
    const u16* __restrict__ fWcat, const int* __restrict__ flagp, u16* __restrict__ msgG,
    const void* __restrict__ emb, const int* __restrict__ Tid, const int* __restrict__ Tsrc,
    const u16* __restrict__ fWz, const u16* __restrict__ fWr, const u16* __restrict__ fWh,
    u16* __restrict__ xzf, u16* __restrict__ xrf, u16* __restrict__ xhf, u16* __restrict__ msgT)
{
  __shared__ char t0[TILE_B];
  int bf = *flagp;
  int lane = threadIdx.x & 63, w = threadIdx.x >> 6;
  int stripe = w * 16, kg = lane >> 4, m16 = lane & 15;
  if (blockIdx.x < GET){
    int blk = blockIdx.x, row0 = blk * 64, arow = row0 + stripe + m16;
    bf16x8 fE[4];
    if (arow < ET){
      int id = Tid[Tsrc[arow]];
      const void* rb = rowdt(emb, (size_t)id, 128, bf);
      #pragma unroll
      for (int ks = 0; ks < 4; ks++){
        float t[8]; load8(rb, ks * 4 + kg, bf, t); fE[ks] = packfrag(t);
      }
    } else {
      #pragma unroll
      for (int ks = 0; ks < 4; ks++) fE[ks] = zfrag();
    }
    f32x4 acc[8];
    uint2 zpk[8];
    INIT_ACC(acc);
    mma_f<4>(fE, fWz, acc);                       // aZ
    #pragma unroll
    for (int nt = 0; nt < 8; nt++){
      zpk[nt] = pack4(acc[nt]);
      *(uint2*)(xzf + fslot(blk, w, nt)) = zpk[nt];
    }
    INIT_ACC(acc);
    mma_f<4>(fE, fWr, acc);                       // aR
    #pragma unroll
    for (int nt = 0; nt < 8; nt++)
      *(uint2*)(xrf + fslot(blk, w, nt)) = pack4(acc[nt]);
    INIT_ACC(acc);
    mma_f<4>(fE, fWh, acc);                       // aH
    #pragma unroll
    for (int nt = 0; nt < 8; nt++){
      *(uint2*)(xhf + fslot(blk, w, nt)) = pack4(acc[nt]);
      float xzv[4]; unp4(zpk[nt], xzv);
      #pragma unroll
      for (int r = 0; r < 4; r++){
        int rt = stripe + (kg << 2) + r;
        int cb = nt * 32 + m16 * 2;
        *(u16*)(t0 + swz(rt, cb)) = f2bf(sigm(xzv[r]) * tanh_(acc[nt][r]));
      }
    }
    wfence();
    repack_store(t0, msgT, row0, ET);
  } else {
    int blk = blockIdx.x - GET, row0 = blk * 64, arow = row0 + stripe + m16;
    bf16x8 fC[4];
    load_catfrag(Gf, Gef, Gsrc, arow, kg, bf, fC);
    f32x4 acc[8]; INIT_ACC(acc);
    mma_f<4>(fC, fWcat, acc);
    #pragma unroll
    for (int nt = 0; nt < 8; nt++)
      #pragma unroll
      for (int r = 0; r < 4; r++){
        int rt = stripe + (kg << 2) + r;
        int cb = nt * 32 + m16 * 2;
        *(u16*)(t0 + swz(rt, cb)) = f2bf(relu_(acc[nt][r]));
      }
    wfence();
    repack_store(t0, msgG, row0, EG);
  }
}

// blocks [0,GET): T GRU iter (sequential accumulator, S + scratch LDS tiles)
// blocks [GET,GET+GEG): G iter (gather-first, base recomputed in regs)
__global__ __launch_bounds__(256, 4) void k_iter(
    const u16* __restrict__ msgInG, u16* __restrict__ msgOutG,
    const void* __restrict__ Gf, const void* __restrict__ Gef, const int* __restrict__ Gsrc,
    const int* __restrict__ rp, const int* __restrict__ col,
    const u16* __restrict__ fWcat, const u16* __restrict__ fW3, const int* __restrict__ flagp,
    const u16* __restrict__ msgInT, u16* __restrict__ msgOutT,
    const u16* __restrict__ fUz, const u16* __restrict__ fUr, const u16* __restrict__ fUh,
    const u16* __restrict__ xzf, const u16* __restrict__ xrf, const u16* __restrict__ xhf)
{
  __shared__ char t0[TILE_B];
  __shared__ char t1[TILE_B];
  int lane = threadIdx.x & 63, w = threadIdx.x >> 6;
  int stripe = w * 16, kg = lane >> 4, m16 = lane & 15;
  if (blockIdx.x < GET){
    // ---- T GRU step ----
    int blk = blockIdx.x, row0 = blk * 64, arow = row0 + stripe + m16;
    float ga[4][8];
    gather_accum(rp + SEG2, col, msgInT, arow, ET, kg, ga);
    bf16x8 fS[4];
    #pragma unroll
    for (int ks = 0; ks < 4; ks++){
      uint4 pk = pack8(ga[ks]);
      *(uint4*)(t0 + swz(stripe + m16, ks * 64 + kg * 16)) = pk;  // S tile
      fS[ks] = as_frag(pk);
    }
    f32x4 acc[8];
    INIT_ACC(acc);
    mma_f<4>(fS, fUr, acc);                      // aR
    wfence();
    #pragma unroll
    for (int nt = 0; nt < 8; nt++){
      uint2 r4 = *(const uint2*)(xrf + fslot(blk, w, nt));
      float xrv[4]; unp4(r4, xrv);
      #pragma unroll
      for (int r = 0; r < 4; r++){
        int rt = stripe + (kg << 2) + r;
        int cb = nt * 32 + m16 * 2;
        float s = bf2f(*(const u16*)(t0 + swz(rt, cb)));
        float rr = sigm(xrv[r] + acc[nt][r]);
        *(u16*)(t1 + swz(rt, cb)) = f2bf(rr * s);   // r*s tile
      }
    }
    wfence();
    bf16x8 fRS[4];
    #pragma unroll
    for (int ks = 0; ks < 4; ks++)
      fRS[ks] = *(const bf16x8*)(t1 + swz(stripe + m16, ks * 64 + kg * 16));
    INIT_ACC(acc);
    mma_f<4>(fRS, fUh, acc);                     // aH
    wfence();
    #pragma unroll
    for (int nt = 0; nt < 8; nt++){
      uint2 h4 = *(const uint2*)(xhf + fslot(blk, w, nt));
      float xhv[4]; unp4(h4, xhv);
      #pragma unroll
      for (int r = 0; r < 4; r++){
        int rt = stripe + (kg << 2) + r;
        int cb = nt * 32 + m16 * 2;
        *(u16*)(t1 + swz(rt, cb)) = f2bf(tanh_(xhv[r] + acc[nt][r]));   // h tile
      }
    }
    wfence();
    bf16x8 fS2[4];
    #pragma unroll
    for (int ks = 0; ks < 4; ks++)
      fS2[ks] = *(const bf16x8*)(t0 + swz(stripe + m16, ks * 64 + kg * 16));
    INIT_ACC(acc);
    mma_f<4>(fS2, fUz, acc);                     // aZ
    wfence();
    #pragma unroll
    for (int nt = 0; nt < 8; nt++){
      uint2 z4 = *(const uint2*)(xzf + fslot(blk, w, nt));
      float xzv[4]; unp4(z4, xzv);
      #pragma unroll
      for (int r = 0; r < 4; r++){
        int rt = stripe + (kg << 2) + r;
        int cb = nt * 32 + m16 * 2;
        float z = sigm(xzv[r] + acc[nt][r]);
        float s = bf2f(*(const u16*)(t0 + swz(rt, cb)));
        float h = bf2f(*(const u16*)(t1 + swz(rt, cb)));
        *(u16*)(t0 + swz(rt, cb)) = f2bf((1.f - z) * s + z * h);
      }
    }
    wfence();
    repack_store(t0, msgOutT, row0, ET);
  } else {
    // ---- G iter: msgOut = relu(Gf[Gsrc]@W1 + Gef@W2 + segsum(msgIn)@W3) ----
    int bf = *flagp;
    int blk = blockIdx.x - GET, row0 = blk * 64, arow = row0 + stripe + m16;
    float ga[4][8];
    gather_accum(rp, col, msgInG, arow, EG, kg, ga);
    bf16x8 fS[4];
    #pragma unroll
    for (int ks = 0; ks < 4; ks++) fS[ks] = packfrag(ga[ks]);
    bf16x8 fC[4];
    load_catfrag(Gf, Gef, Gsrc, arow, kg, bf, fC);   // latency hides under fS@W3 mma
    f32x4 acc[8]; INIT_ACC(acc);
    mma_f<4>(fS, fW3, acc);
    mma_f<4>(fC, fWcat, acc);
    #pragma unroll
    for (int nt = 0; nt < 8; nt++)
      #pragma unroll
      for (int r = 0; r < 4; r++){
        int rt = stripe + (kg << 2) + r;
        int cb = nt * 32 + m16 * 2;
        *(u16*)(t0 + swz(rt, cb)) = f2bf(relu_(acc[nt][r]));
      }
    wfence();
    repack_store(t0, msgOutG, row0, EG);
  }
}

// blocks [0,GNT): out_T = relu(emb[Tid]@U1T + segsum(msgT)@U2T)
// blocks [GNT,GNT+GNG): out_G = relu(Gf@U1G + segsum(msgG)@U2G)
__global__ __launch_bounds__(256, 4) void k_readout(
    const void* __restrict__ Gf, const u16* __restrict__ msgG,
    const int* __restrict__ rp, const int* __restrict__ col,
    const u16* __restrict__ fU1G, const u16* __restrict__ fU2G,
    const void* __restrict__ emb, const int* __restrict__ Tid, const u16* __restrict__ msgT,
    const u16* __restrict__ fU1T, const u16* __restrict__ fU2T,
    const int* __restrict__ flagp, float* __restrict__ out)
{
  int bf = *flagp;
  int lane = threadIdx.x & 63, w = threadIdx.x >> 6;
  int stripe = w * 16, kg = lane >> 4, m16 = lane & 15;
  if (blockIdx.x < GNT){
    int row0 = blockIdx.x * 64, arow = row0 + stripe + m16;
    float ga[4][8];
    gather_accum(rp + SEG3, col, msgT, arow, NT, kg, ga);
    bf16x8 fS[4];
    #pragma unroll
    for (int ks = 0; ks < 4; ks++) fS[ks] = packfrag(ga[ks]);
    bf16x8 fE[4];
    if (arow < NT){
      int id = Tid[arow];
      const void* rb = rowdt(emb, (size_t)id, 128, bf);
      #pragma unroll
      for (int ks = 0; ks < 4; ks++){
        float t[8]; load8(rb, ks * 4 + kg, bf, t); fE[ks] = packfrag(t);
      }
    } else {
      #pragma unroll
      for (int ks = 0; ks < 4; ks++) fE[ks] = zfrag();
    }
    f32x4 acc[8]; INIT_ACC(acc);
    mma_f<4>(fS, fU2T, acc);
    mma_f<4>(fE, fU1T, acc);
    #pragma unroll
    for (int nt = 0; nt < 8; nt++)
      #pragma unroll
      for (int r = 0; r < 4; r++){
        int R = row0 + stripe + (kg << 2) + r;
        if (R < NT) out[(size_t)(NG + R) * 128 + nt * 16 + m16] = relu_(acc[nt][r]);
      }
  } else {
    int row0 = (blockIdx.x - GNT) * 64, arow = row0 + stripe + m16;
    float ga[4][8];
    gather_accum(rp + SEG1, col, msgG, arow, NG, kg, ga);
    bf16x8 fS[4];
    #pragma unroll
    for (int ks = 0; ks < 4; ks++) fS[ks] = packfrag(ga[ks]);
    bf16x8 fG[2];
    if (arow < NG){
      const void* ra = rowdt(Gf, (size_t)arow, 64, bf);
      float t[8];
      load8(ra, kg, bf, t);     fG[0] = packfrag(t);
      load8(ra, 4 + kg, bf, t); fG[1] = packfrag(t);
    } else { fG[0] = zfrag(); fG[1] = zfrag(); }
    f32x4 acc[8]; INIT_ACC(acc);
    mma_f<4>(fS, fU2G, acc);
    mma_f<2>(fG, fU1G, acc);
    #pragma unroll
    for (int nt = 0; nt < 8; nt++)
      #pragma unroll
      for (int r = 0; r < 4; r++){
        int R = row0 + stripe + (kg << 2) + r;
        if (R < NG) out[(size_t)R * 128 + nt * 16 + m16] = relu_(acc[nt][r]);
      }
  }
}

// ---------------- host launcher ----------------
extern "C" void kernel_launch(void* const* d_in, const int* in_sizes, int n_in,
                              void* d_out, int out_size, void* d_ws, size_t ws_size,
                              hipStream_t stream)
{
  const void* G_f      = d_in[0];
  const void* G_ef     = d_in[1];
  const int*  G_src    = (const int*)d_in[2];
  const int*  G_dst    = (const int*)d_in[3];
  const int*  G_lg_src = (const int*)d_in[4];
  const int*  G_lg_dst = (const int*)d_in[5];
  const int*  T_id     = (const int*)d_in[6];
  const int*  T_src    = (const int*)d_in[7];
  const int*  T_dst    = (const int*)d_in[8];
  const int*  T_lg_src = (const int*)d_in[9];
  const int*  T_lg_dst = (const int*)d_in[10];
  const void* emb      = d_in[11];
  float* out = (float*)d_out;
  (void)in_sizes; (void)n_in; (void)out_size; (void)ws_size;

  size_t off = 0;
  auto alloc = [&](size_t bytes) -> char* {
    char* p = (char*)d_ws + off;
    off += (bytes + 255) & ~(size_t)255;
    return p;
  };

  int*   flag = (int*)alloc(256);
  float* wm   = (float*)alloc(sizeof(float) * 188416);
  u16*   frag = (u16*)alloc(2 * 46 * 4096);
  const u16* fWcat = frag;
  const u16* fW3   = frag + (size_t)4  * 4096;
  const u16* fU1G  = frag + (size_t)8  * 4096;
  const u16* fU2G  = frag + (size_t)10 * 4096;
  const u16* fWz   = frag + (size_t)14 * 4096;
  const u16* fUz   = frag + (size_t)18 * 4096;
  const u16* fWr   = frag + (size_t)22 * 4096;
  const u16* fUr   = frag + (size_t)26 * 4096;
  const u16* fWh   = frag + (size_t)30 * 4096;
  const u16* fUh   = frag + (size_t)34 * 4096;
  const u16* fU1T  = frag + (size_t)38 * 4096;
  const u16* fU2T  = frag + (size_t)42 * 4096;

  int* rp   = (int*)alloc(sizeof(int) * (NSEG_ALL + 1));
  int* col  = (int*)alloc(sizeof(int) * NE_PAD);
  int* cnt  = (int*)alloc(sizeof(int) * 2 * NSEG_ALL);
  int* csum = (int*)alloc(sizeof(int) * 256);
  u16* msgGA = (u16*)alloc((size_t)(EG + 1) * 128 * 2);
  u16* msgGB = (u16*)alloc((size_t)(EG + 1) * 128 * 2);
  u16* xzf   = (u16*)alloc((size_t)GET * 8192 * 2);
  u16* xrf   = (u16*)alloc((size_t)GET * 8192 * 2);
  u16* xhf   = (u16*)alloc((size_t)GET * 8192 * 2);
  u16* msgTA = (u16*)alloc((size_t)(ET + 1) * 128 * 2);
  u16* msgTB = (u16*)alloc((size_t)(ET + 1) * 128 * 2);
  // total ws ≈ 360 MB

  // setup: dtype flag -> weight mirrors -> fragment tables
  k_sniff<<<1, 256, 0, stream>>>((const u32*)G_ef, flag);
  k_cvt_all<<<(188416 + 255) / 256, 256, 0, stream>>>(
      d_in[12], d_in[13], d_in[14], d_in[15], d_in[16], d_in[17], d_in[18],
      d_in[19], d_in[20], d_in[21], d_in[22], d_in[23], d_in[24], wm, flag);
  k_mkfrag_all<<<46, 512, 0, stream>>>(wm, frag);
  k_zero_dummy<<<1, 128, 0, stream>>>(msgGA, msgGB, msgTA, msgTB);

  // unified padded CSR build
  hipMemsetAsync(cnt, 0, sizeof(int) * 2 * NSEG_ALL, stream);
  k_hist_all<<<(NE_ALL + 255) / 256, 256, 0, stream>>>(G_lg_dst, G_dst, T_lg_dst, T_dst, cnt);
  int nch = (NSEG_ALL + 4095) / 4096;
  k_scan1<<<nch, 256, 0, stream>>>(cnt, NSEG_ALL, csum);
  k_scan2<<<1, 64, 0, stream>>>(csum, nch, rp, NSEG_ALL);
  k_scan3<<<nch, 256, 0, stream>>>(cnt, NSEG_ALL, csum, rp);
  k_fill_all<<<(NE_ALL + 255) / 256, 256, 0, stream>>>(
      G_lg_dst, G_lg_src, G_dst, T_lg_dst, T_lg_src, T_dst, rp, cnt + NSEG_ALL, col);
  k_fill_pad<<<(NSEG_ALL + 255) / 256, 256, 0, stream>>>(cnt, rp, col);

  // merged pipeline (5 launches, T blocks first)
  k_init<<<GET + GEG, 256, 0, stream>>>(G_f, G_ef, G_src, fWcat, flag, msgGA,
                                        emb, T_id, T_src, fWz, fWr, fWh, xzf, xrf, xhf, msgTA);
  k_iter<<<GET + GEG, 256, 0, stream>>>(msgGA, msgGB, G_f, G_ef, G_src, rp, col, fWcat, fW3, flag,
                                        msgTA, msgTB, fUz, fUr, fUh, xzf, xrf, xhf);
  k_iter<<<GET + GEG, 256, 0, stream>>>(msgGB, msgGA, G_f, G_ef, G_src, rp, col, fWcat, fW3, flag,
                                        msgTB, msgTA, fUz, fUr, fUh, xzf, xrf, xhf);
  k_iter<<<GET + GEG, 256, 0, stream>>>(msgGA, msgGB, G_f, G_ef, G_src, rp, col, fWcat, fW3, flag,
                                        msgTA, msgTB, fUz, fUr, fUh, xzf, xrf, xhf);
  k_readout<<<GNT + GNG, 256, 0, stream>>>(G_f, msgGB, rp, col, fU1G, fU2G,
                                           emb, T_id, msgTB, fU1T, fU2T, flag, out);
}